// Round 13
// baseline (744.657 us; speedup 1.0000x reference)
//
#include <hip/hip_runtime.h>
#include <stdint.h>

// Problem constants
#define BB 2
#define SS 2048
#define DD 4096
#define NH 32
#define NKVH 8
#define HD 128
#define QKVN 6144          // (32 + 2*8) * 128
#define MROWS (BB * SS)    // 4096
#define LOG2E 1.4426950408889634f

typedef short bf16x8 __attribute__((ext_vector_type(8)));   // 8 bf16 in 4 VGPRs
typedef float f32x4 __attribute__((ext_vector_type(4)));

__device__ __forceinline__ short f32_bf16(float f) {
  union { float f; unsigned u; } c; c.f = f;
  unsigned r = (c.u + 0x7fffu + ((c.u >> 16) & 1u)) >> 16;   // RNE
  return (short)r;
}
__device__ __forceinline__ float bf16_f32(short h) {
  union { unsigned u; float f; } c; c.u = ((unsigned)(unsigned short)h) << 16;
  return c.f;
}

// async global->LDS, 16B per lane. LDS dest must be wave-uniform base + lane*16.
__device__ __forceinline__ void async16(const void* g, void* l) {
  __builtin_amdgcn_global_load_lds(
      (const __attribute__((address_space(1))) unsigned int*)(uintptr_t)g,
      (__attribute__((address_space(3))) unsigned int*)(uintptr_t)l,
      16, 0, 0);
}

// ---------------------------------------------------------------- cast f32 -> bf16
__global__ __launch_bounds__(256) void cast_bf16_kernel(const float* __restrict__ in,
                                                        short* __restrict__ out, int n4) {
  int i = blockIdx.x * 256 + threadIdx.x;
  if (i >= n4) return;
  float4 v = ((const float4*)in)[i];
  short4 o;
  o.x = f32_bf16(v.x); o.y = f32_bf16(v.y); o.z = f32_bf16(v.z); o.w = f32_bf16(v.w);
  ((short4*)out)[i] = o;
}

// ---------------------------------------------------------------- rope tables
__global__ __launch_bounds__(256) void rope_tables_kernel(float* __restrict__ cosT,
                                                          float* __restrict__ sinT) {
  int idx = blockIdx.x * 256 + threadIdx.x;   // S*64
  if (idx >= SS * 64) return;
  int s = idx >> 6, t = idx & 63;
  float invf = exp2f(-(float)t * (18.931568569324174f / 64.0f));  // log2(500000)/64
  float fr = (float)s * invf;
  float sv, cv;
  sincosf(fr, &sv, &cv);
  cosT[idx] = cv;
  sinT[idx] = sv;
}

// ---------------------------------------------------------------- rope + scatter (Q,K only)
__global__ __launch_bounds__(256) void rope_scatter_kernel(const short* __restrict__ qkv,
    const float* __restrict__ cosT, const float* __restrict__ sinT,
    short* __restrict__ Qb, short* __restrict__ Kb) {
  int idx = blockIdx.x * 256 + threadIdx.x;   // B*S*40*64
  if (idx >= BB * SS * 40 * 64) return;
  int t = idx & 63;
  int hh = (idx >> 6) % 40;
  int bs = (idx >> 6) / 40;
  int s = bs & (SS - 1);
  int b = bs >> 11;
  const short* row = qkv + (long)bs * QKVN + hh * HD;
  float x1 = bf16_f32(row[t]);
  float x2 = bf16_f32(row[t + 64]);
  float c = cosT[(s << 6) + t], sn = sinT[(s << 6) + t];
  float o1 = x1 * c - x2 * sn;
  float o2 = x2 * c + x1 * sn;
  if (hh < 32) {
    const float sc = 0.08838834764831845f;  // 1/sqrt(128), folded into Q
    o1 *= sc; o2 *= sc;
    short* q = Qb + ((long)(b * NH + hh) * SS + s) * HD;
    q[t] = f32_bf16(o1); q[t + 64] = f32_bf16(o2);
  } else {
    short* k = Kb + ((long)(b * NKVH + (hh - 32)) * SS + s) * HD;
    k[t] = f32_bf16(o1); k[t + 64] = f32_bf16(o2);
  }
}

// ---------------------------------------------------------------- V transpose scatter
__global__ __launch_bounds__(256) void v_scatter_kernel(const short* __restrict__ qkv,
                                                        short* __restrict__ Vtb) {
  int bid = blockIdx.x;                 // 512 = B * NKVH * (SS/64)
  int s0 = (bid & 31) << 6;
  int kvh = (bid >> 5) & 7;
  int b = bid >> 8;
  const short* src = qkv + (long)(b * SS + s0) * QKVN + 5120 + kvh * HD;
  short* dst = Vtb + ((long)(b * NKVH + kvh) * HD) * SS + s0;
  int w = threadIdx.x >> 6, l = threadIdx.x & 63;
#pragma unroll
  for (int it = 0; it < 32; ++it) {
    int d = (it << 2) + w;
    dst[(long)d * SS + l] = src[(long)l * QKVN + d];
  }
}

// ---------------------------------------------------------------- GEMM 256x256 BK=64, counted vmcnt (T4)
// Round 13: rounds 9-12 established the drain-0 schedule is the cap (MfmaUtil
// pinned ~35% across blocks/CU, BK, FETCH variations = m218's "phase+drain0 ~
// 1-phase" at 634-770 TF). Single change vs round 10: COUNTED vmcnt.
//   top of tile t: issue STAGE(t+1) (8 loads/thread, buf^1) -> vmcnt(8)
//     (retires own STAGE(t); STAGE(t+1) stays IN FLIGHT across all phase
//     barriers) -> sched_barrier -> s_barrier (RAW: buf[cur] fully written).
//   tile end: bare s_barrier (WAR: all waves past buf[cur] reads before
//     next iteration's STAGE writes it). Never drain to 0 mid-loop (m218:
//     counted-vs-drain0 = +38-73%). Last tile: vmcnt(0) once.
// Swizzle slot^=row&7 both-sides (rule #21, 0 conflicts verified round 9);
// square per-XCD supertiles (round 10, FETCH 352->180MB); plain
// __launch_bounds__(512) — NEVER pass min-waves (toolchain caps VGPR=256/N;
// rounds 6/11 spilled catastrophically).
#define STAGE256(kt, bsel)                                                          \
  {                                                                                 \
    const long kbase_ = (long)(kt) << 6;                                            \
    _Pragma("unroll") for (int i_ = 0; i_ < 4; i_++) {                              \
      const int idx_ = tid + i_ * 512;                                              \
      const int row_ = idx_ >> 3, slot_ = idx_ & 7;                                 \
      const int ss_ = slot_ ^ (row_ & 7);                                           \
      async16(Ag0 + (long)row_ * K + kbase_ + ss_ * 8,                              \
              &Abuf[bsel][row_ * 64 + slot_ * 8]);                                  \
      async16(Bg0 + (long)row_ * K + kbase_ + ss_ * 8,                              \
              &Bbuf[bsel][row_ * 64 + slot_ * 8]);                                  \
    }                                                                               \
  }

#define GPHASE(p, LASTP)                                                            \
  {                                                                                 \
    bf16x8 afr[2][2];                                                               \
    _Pragma("unroll") for (int mi = 0; mi < 2; mi++)                                \
      _Pragma("unroll") for (int kk = 0; kk < 2; kk++)                              \
        afr[mi][kk] = *(const bf16x8*)&Ac[(((p) * 2 + mi) * 16 + l16) * 64 +        \
                                          ((((kk << 2) + quad) ^ xr) << 3)];        \
    __builtin_amdgcn_s_barrier();                                                   \
    asm volatile("s_waitcnt lgkmcnt(0)" ::: "memory");                              \
    __builtin_amdgcn_sched_barrier(0);                                              \
    __builtin_amdgcn_s_setprio(1);                                                  \
    _Pragma("unroll") for (int mi = 0; mi < 2; mi++)                                \
      _Pragma("unroll") for (int nr = 0; nr < 4; nr++)                              \
        _Pragma("unroll") for (int kk = 0; kk < 2; kk++)                            \
          acc[(p) * 2 + mi][nr] = __builtin_amdgcn_mfma_f32_16x16x32_bf16(          \
              afr[mi][kk], bfr[nr][kk], acc[(p) * 2 + mi][nr], 0, 0, 0);            \
    __builtin_amdgcn_s_setprio(0);                                                  \
    if (!(LASTP)) __builtin_amdgcn_s_barrier();                                     \
  }

template <int STORE_BF16>
__global__ __launch_bounds__(512) void gemm256_kernel(const short* __restrict__ A,
    const short* __restrict__ B, void* __restrict__ Cv, int M, int N, int K, int gx) {
  __shared__ __align__(16) short Abuf[2][256 * 64];   // 64KB
  __shared__ __align__(16) short Bbuf[2][256 * 64];   // 64KB
  const int tid = threadIdx.x;
  const int lane = tid & 63, wave = tid >> 6;
  const int quad = lane >> 4, l16 = lane & 15;
  const int wm = wave >> 2;          // 0..1: M-half
  const int wn = wave & 3;           // 0..3: N-quarter
  const int xr = l16 & 7;            // read-side XOR key

  // Square per-XCD supertile decode (gy = 16 both call sites):
  const int bid = (int)blockIdx.x;
  const int xcd = bid & 7;
  const int i = bid >> 3;            // 0 .. nwg/8-1
  const int cpb = gx >> 2;           // patch cols (6 QKV, 4 O-proj)
  const int prow = i & 7;            // patch rows = 8 (gy/2)
  const int pcol = i >> 3;
  const int m0 = (((xcd >> 2) << 3) + prow) << 8;
  const int n0 = ((xcd & 3) * cpb + pcol) << 8;

  const short* Ag0 = A + (long)m0 * K;
  const short* Bg0 = B + (long)n0 * K;

  f32x4 acc[8][4];
#pragma unroll
  for (int mr = 0; mr < 8; mr++)
#pragma unroll
    for (int nr = 0; nr < 4; nr++) acc[mr][nr] = (f32x4){0.f, 0.f, 0.f, 0.f};

  const int nk = K >> 6;

  // prologue: stage tile 0 into buf0, drain once, align
  STAGE256(0, 0);
  asm volatile("s_waitcnt vmcnt(0)" ::: "memory");
  __builtin_amdgcn_sched_barrier(0);
  __builtin_amdgcn_s_barrier();

  int cur = 0;
#pragma unroll 1
  for (int kt = 0; kt < nk; ++kt) {
    // counted pipeline top: issue next tile, retire ONLY the current tile
    if (kt + 1 < nk) {
      if (cur == 0) { STAGE256(kt + 1, 1); } else { STAGE256(kt + 1, 0); }
      asm volatile("s_waitcnt vmcnt(8)" ::: "memory");   // STAGE(kt) done; kt+1 flies
    } else {
      asm volatile("s_waitcnt vmcnt(0)" ::: "memory");   // last tile: full drain
    }
    __builtin_amdgcn_sched_barrier(0);
    __builtin_amdgcn_s_barrier();                        // all waves: buf[cur] ready

    const short* Ac = &Abuf[cur][wm * 128 * 64];
    const short* Bc = &Bbuf[cur][wn * 64 * 64];

    // B fragments for the whole tile (8 x ds_read_b128)
    bf16x8 bfr[4][2];
#pragma unroll
    for (int nr = 0; nr < 4; nr++)
#pragma unroll
      for (int kk = 0; kk < 2; kk++)
        bfr[nr][kk] = *(const bf16x8*)&Bc[(nr * 16 + l16) * 64 +
                                          ((((kk << 2) + quad) ^ xr) << 3)];
    GPHASE(0, 0)
    GPHASE(1, 0)
    GPHASE(2, 0)
    GPHASE(3, 1)

    // tile end: WAR barrier only (no drain) — next iter's STAGE overwrites
    // buf[cur] one flip later; all waves must be past their reads first.
    __builtin_amdgcn_s_barrier();
    cur ^= 1;
  }

  // epilogue
#pragma unroll
  for (int mr = 0; mr < 8; mr++)
#pragma unroll
    for (int nr = 0; nr < 4; nr++)
#pragma unroll
      for (int r = 0; r < 4; r++) {
        long row = m0 + wm * 128 + mr * 16 + quad * 4 + r;
        long col = n0 + wn * 64 + nr * 16 + l16;
        if (STORE_BF16)
          ((short*)Cv)[row * N + col] = f32_bf16(acc[mr][nr][r]);
        else
          ((float*)Cv)[row * N + col] = acc[mr][nr][r];
      }
}

// ---------------------------------------------------------------- flash attention v9 (proven round 9)
// Block-cooperative K+V LDS staging (4x traffic cut), uniform 34-step causal
// pairing, counted-vmcnt pipeline, XOR-swizzled tiles. Frozen.
#define PSS 72   // P LDS row stride (elements): 144B, 16B-multiple

#define STAGEK(j0_)                                                                 \
  {                                                                                 \
    _Pragma("unroll") for (int i_ = 0; i_ < 4; i_++) {                              \
      const int idx_ = tid + i_ * 256;                                              \
      const int r_ = idx_ >> 4, s_ = idx_ & 15;                                     \
      async16(Kb + (long)((j0_) + r_) * HD + ((s_ ^ (r_ & 7)) << 3),                \
              &Ks[r_ * 128 + (s_ << 3)]);                                           \
    }                                                                               \
  }

#define STAGEV(j0_)                                                                 \
  {                                                                                 \
    _Pragma("unroll") for (int i_ = 0; i_ < 4; i_++) {                              \
      const int idx_ = tid + i_ * 256;                                              \
      const int r_ = idx_ >> 3, s_ = idx_ & 7;                                      \
      async16(Vb + (long)r_ * SS + (j0_) + ((s_ ^ (r_ & 7)) << 3),                  \
              &Vs[r_ * 64 + (s_ << 3)]);                                            \
    }                                                                               \
  }

__global__ __launch_bounds__(256, 2) void flash_attn_kernel(const short* __restrict__ Q,
    const short* __restrict__ Kt, const short* __restrict__ Vt, short* __restrict__ O) {
  __shared__ __align__(16) short Ks[64 * 128];   // 16KB K tile (swizzled)
  __shared__ __align__(16) short Vs[128 * 64];   // 16KB V tile (swizzled, [d][key])
  __shared__ __align__(16) short Ps[4][32 * PSS];
  const int tid = threadIdx.x;
  const int wave = tid >> 6, lane = tid & 63;
  const int quad = lane >> 4, l16 = lane & 15;
  const int k7 = l16 & 7;                        // read-side XOR key

  // XCD co-location decode: 512 blocks; blocks sharing (b,kvh) share bid%8.
  const int flat = blockIdx.x;
  const int xcd = flat & 7;
  const int kk_ = flat >> 3;          // 0..63
  const int gsel = kk_ >> 5;          // 0..1
  const int jj = kk_ & 31;            // 0..31
  const int g = xcd * 2 + gsel;       // 0..15 = (b,kvh) group
  const int b = g >> 3, kvh = g & 7;
  const int h = (kvh << 2) + (jj >> 3);
  const int qb0 = jj & 7;

  const short* Kb = Kt + (long)(b * NKVH + kvh) * SS * HD;
  const short* Vb = Vt + (long)(b * NKVH + kvh) * HD * SS;
  short* Pw = &Ps[wave][0];

  // Two causal-complementary 128-row block-tiles: steps = (2qb+2)+(32-2qb) = 34.
#pragma unroll 1
  for (int half = 0; half < 2; half++) {
    const int qb = half ? (15 - qb0) : qb0;
    const int q0b = qb << 7;
    const int q0w = q0b + (wave << 5);
    const int nfull = q0w >> 6;            // this wave's last (masked) tile
    const int tsteps = (q0b >> 6) + 2;     // block-uniform step count

    const short* Qw = Q + ((long)(b * NH + h) * SS + q0w) * HD;
    bf16x8 qf[2][4];
#pragma unroll
    for (int i = 0; i < 2; i++)
#pragma unroll
      for (int kk = 0; kk < 4; kk++)
        qf[i][kk] = *(const bf16x8*)&Qw[(i * 16 + l16) * HD + kk * 32 + quad * 8];
    // drain Q loads so staging vmcnt counts stay exact
    asm volatile("s_waitcnt vmcnt(0)" ::: "memory");
    __builtin_amdgcn_sched_barrier(0);

    f32x4 oacc[2][8];
#pragma unroll
    for (int i = 0; i < 2; i++)
#pragma unroll
      for (int jo = 0; jo < 8; jo++) oacc[i][jo] = (f32x4){0.f, 0.f, 0.f, 0.f};
    float l_i[2][4];
#pragma unroll
    for (int i = 0; i < 2; i++)
#pragma unroll
      for (int r = 0; r < 4; r++) l_i[i][r] = 0.f;

    // prologue: stage K[0] then V[0]  (outstanding: K 4 oldest, V 4 newest)
    STAGEK(0)
    STAGEV(0)

#pragma unroll 1
    for (int t = 0; t < tsteps; t++) {
      const int j0 = t << 6;
      const bool active = (t <= nfull);
      const bool havenext = (t + 1 < tsteps);

      // top: retire K[t] (V[t] may still fly), align block
      asm volatile("s_waitcnt vmcnt(4)" ::: "memory");
      __builtin_amdgcn_sched_barrier(0);
      __builtin_amdgcn_s_barrier();
      __builtin_amdgcn_sched_barrier(0);

      f32x4 sc[2][4];
      if (active) {
        // QK from LDS K tile
        bf16x8 kf[16];
#pragma unroll
        for (int kk = 0; kk < 4; kk++)
#pragma unroll
          for (int j = 0; j < 4; j++)
            kf[kk * 4 + j] = *(const bf16x8*)&Ks[(j * 16 + l16) * 128 +
                                                 ((((kk << 2) + quad) ^ k7) << 3)];
#pragma unroll
        for (int i = 0; i < 2; i++)
#pragma unroll
          for (int j = 0; j < 4; j++) sc[i][j] = (f32x4){0.f, 0.f, 0.f, 0.f};
        __builtin_amdgcn_s_setprio(1);
#pragma unroll
        for (int kk = 0; kk < 4; kk++)
#pragma unroll
          for (int i = 0; i < 2; i++)
#pragma unroll
            for (int j = 0; j < 4; j++)
              sc[i][j] = __builtin_amdgcn_mfma_f32_16x16x32_bf16(
                  qf[i][kk], kf[kk * 4 + j], sc[i][j], 0, 0, 0);
        __builtin_amdgcn_s_setprio(0);
      }

      // all waves done reading Ks[t]
      __builtin_amdgcn_s_barrier();
      __builtin_amdgcn_sched_barrier(0);
      if (havenext) STAGEK(j0 + 64)   // hides under exp/P/PV

      if (active) {
        if (t == nfull) {
#pragma unroll
          for (int i = 0; i < 2; i++)
#pragma unroll
            for (int r = 0; r < 4; r++) {
              int row = q0w + i * 16 + quad * 4 + r;
#pragma unroll
              for (int j = 0; j < 4; j++) {
                int col = j0 + j * 16 + l16;
                if (col > row) sc[i][j][r] = -3.0e38f;
              }
            }
        }
        // p = exp(s); per-lane row-sum partials (max-free)
#pragma unroll
        for (int i = 0; i < 2; i++)
#pragma unroll
          for (int r = 0; r < 4; r++) {
            float ps = 0.f;
#pragma unroll
            for (int j = 0; j < 4; j++) {
              float p = __builtin_amdgcn_exp2f(sc[i][j][r] * LOG2E);
              sc[i][j][r] = p;
              ps += p;
            }
            l_i[i][r] += ps;
          }
        // P: C-layout -> per-wave LDS -> A-layout
#pragma unroll
        for (int i = 0; i < 2; i++)
#pragma unroll
          for (int j = 0; j < 4; j++)
#pragma unroll
            for (int r = 0; r < 4; r++)
              Pw[(i * 16 + quad * 4 + r) * PSS + j * 16 + l16] = f32_bf16(sc[i][j][r]);
      }

      // retire V[t] (K[t+1] may still fly), align block
      if (havenext) {
        asm volatile("s_waitcnt vmcnt(4)" ::: "memory");
      } else {
        asm volatile("s_waitcnt vmcnt(0)" ::: "memory");
      }
      __builtin_amdgcn_sched_barrier(0);
      __builtin_amdgcn_s_barrier();
      __builtin_amdgcn_sched_barrier(0);

      if (active) {
        asm volatile("s_waitcnt lgkmcnt(0)" ::: "memory");   // P writes landed
        bf16x8 ap[2][2];
#pragma unroll
        for (int kv = 0; kv < 2; kv++) {
          ap[kv][0] = *(const bf16x8*)&Pw[l16 * PSS + kv * 32 + quad * 8];
          ap[kv][1] = *(const bf16x8*)&Pw[(16 + l16) * PSS + kv * 32 + quad * 8];
        }
        // PV from LDS V tile
        __builtin_amdgcn_s_setprio(1);
#pragma unroll
        for (int jo = 0; jo < 8; jo++) {
          bf16x8 v0 = *(const bf16x8*)&Vs[(jo * 16 + l16) * 64 + ((quad ^ k7) << 3)];
          oacc[0][jo] = __builtin_amdgcn_mfma_f32_16x16x32_bf16(ap[0][0], v0,
                                                                oacc[0][jo], 0, 0, 0);
          oacc[1][jo] = __builtin_amdgcn_mfma_f32_16x16x32_bf16(ap[0][1], v0,
                                                                oacc[1][jo], 0, 0, 0);
        }
#pragma unroll
        for (int jo = 0; jo < 8; jo++) {
          bf16x8 v1 = *(const bf16x8*)&Vs[(jo * 16 + l16) * 64 +
                                          (((4 + quad) ^ k7) << 3)];
          oacc[0][jo] = __builtin_amdgcn_mfma_f32_16x16x32_bf16(ap[1][0], v1,
                                                                oacc[0][jo], 0, 0, 0);
          oacc[1][jo] = __builtin_amdgcn_mfma_f32_16x16x32_bf16(ap[1][1], v1,
                                                                oacc[1][jo], 0, 0, 0);
        }
        __builtin_amdgcn_s_setprio(0);
      }

      // all waves done reading Vs[t]
      __builtin_amdgcn_s_barrier();
      __builtin_amdgcn_sched_barrier(0);
      if (havenext) STAGEV(j0 + 64)   // hides under next QK
    }

    // epilogue: reduce l across the 16 lanes of each quad (once), store
    short* Ob = O + (long)(b * SS + q0w) * DD + h * HD;
#pragma unroll
    for (int i = 0; i < 2; i++)
#pragma unroll
      for (int r = 0; r < 4; r++) {
        float s = l_i[i][r];
        s += __shfl_xor(s, 1, 64);
        s += __shfl_xor(s, 2, 64);
        s += __shfl_xor(s, 4, 64);
        s += __shfl_xor(s, 8, 64);
        float inv = 1.0f / s;
        int row = i * 16 + quad * 4 + r;
#pragma unroll
        for (int jo = 0; jo < 8; jo++)
          Ob[(long)row * DD + jo * 16 + l16] = f32_bf16(oacc[i][jo][r] * inv);
      }
  }
}

// ---------------------------------------------------------------- launch
extern "C" void kernel_launch(void* const* d_in, const int* in_sizes, int n_in,
                              void* d_out, int out_size, void* d_ws, size_t ws_size,
                              hipStream_t stream) {
  (void)in_sizes; (void)n_in; (void)out_size; (void)ws_size;
  const float* x    = (const float*)d_in[0];
  const float* Wqkv = (const float*)d_in[1];
  const float* Wo   = (const float*)d_in[2];
  char* ws = (char*)d_ws;
  short* xb    = (short*)(ws + 0);            // x bf16 (33.5MB); reused as attn out
  short* wqkvb = (short*)(ws + 33554432);     // Wqkv bf16 (50.3MB)
  short* qkvb  = (short*)(ws + 83886080);     // qkv (50.3MB); reused as Wo bf16
  short* Qb    = (short*)(ws + 134217728);    // 33.5MB
  short* Kb    = (short*)(ws + 167772160);    // 8.4MB
  short* Vtb   = (short*)(ws + 176160768);    // 8.4MB
  float* cosT  = (float*)(ws + 184549376);    // 0.5MB
  float* sinT  = (float*)(ws + 185073664);    // 0.5MB
  short* wob   = qkvb;
  short* attnb = xb;

  cast_bf16_kernel<<<16384, 256, 0, stream>>>(x, xb, 4194304);
  cast_bf16_kernel<<<24576, 256, 0, stream>>>(Wqkv, wqkvb, 6291456);
  gemm256_kernel<1><<<dim3((QKVN / 256) * (MROWS / 256)), 512, 0, stream>>>(
      xb, wqkvb, (void*)qkvb, MROWS, QKVN, DD, QKVN / 256);
  rope_tables_kernel<<<512, 256, 0, stream>>>(cosT, sinT);
  rope_scatter_kernel<<<40960, 256, 0, stream>>>(qkvb, cosT, sinT, Qb, Kb);
  v_scatter_kernel<<<512, 256, 0, stream>>>(qkvb, Vtb);
  cast_bf16_kernel<<<16384, 256, 0, stream>>>(Wo, wob, 4194304);   // overwrites qkvb (dead)
  flash_attn_kernel<<<512, 256, 0, stream>>>(Qb, Kb, Vtb, attnb);
  gemm256_kernel<0><<<dim3((DD / 256) * (MROWS / 256)), 512, 0, stream>>>(
      attnb, wob, d_out, MROWS, DD, DD, DD / 256);
}

// Round 14
// 723.599 us; speedup vs baseline: 1.0291x; 1.0291x over previous
//
#include <hip/hip_runtime.h>
#include <stdint.h>

// Problem constants
#define BB 2
#define SS 2048
#define DD 4096
#define NH 32
#define NKVH 8
#define HD 128
#define QKVN 6144          // (32 + 2*8) * 128
#define MROWS (BB * SS)    // 4096
#define LOG2E 1.4426950408889634f

typedef short bf16x8 __attribute__((ext_vector_type(8)));   // 8 bf16 in 4 VGPRs
typedef float f32x4 __attribute__((ext_vector_type(4)));

__device__ __forceinline__ short f32_bf16(float f) {
  union { float f; unsigned u; } c; c.f = f;
  unsigned r = (c.u + 0x7fffu + ((c.u >> 16) & 1u)) >> 16;   // RNE
  return (short)r;
}
__device__ __forceinline__ float bf16_f32(short h) {
  union { unsigned u; float f; } c; c.u = ((unsigned)(unsigned short)h) << 16;
  return c.f;
}

// async global->LDS, 16B per lane. LDS dest must be wave-uniform base + lane*16.
__device__ __forceinline__ void async16(const void* g, void* l) {
  __builtin_amdgcn_global_load_lds(
      (const __attribute__((address_space(1))) unsigned int*)(uintptr_t)g,
      (__attribute__((address_space(3))) unsigned int*)(uintptr_t)l,
      16, 0, 0);
}

// ---------------------------------------------------------------- cast f32 -> bf16
__global__ __launch_bounds__(256) void cast_bf16_kernel(const float* __restrict__ in,
                                                        short* __restrict__ out, int n4) {
  int i = blockIdx.x * 256 + threadIdx.x;
  if (i >= n4) return;
  float4 v = ((const float4*)in)[i];
  short4 o;
  o.x = f32_bf16(v.x); o.y = f32_bf16(v.y); o.z = f32_bf16(v.z); o.w = f32_bf16(v.w);
  ((short4*)out)[i] = o;
}

// ---------------------------------------------------------------- rope tables
__global__ __launch_bounds__(256) void rope_tables_kernel(float* __restrict__ cosT,
                                                          float* __restrict__ sinT) {
  int idx = blockIdx.x * 256 + threadIdx.x;   // S*64
  if (idx >= SS * 64) return;
  int s = idx >> 6, t = idx & 63;
  float invf = exp2f(-(float)t * (18.931568569324174f / 64.0f));  // log2(500000)/64
  float fr = (float)s * invf;
  float sv, cv;
  sincosf(fr, &sv, &cv);
  cosT[idx] = cv;
  sinT[idx] = sv;
}

// ---------------------------------------------------------------- rope + scatter (Q,K only)
__global__ __launch_bounds__(256) void rope_scatter_kernel(const short* __restrict__ qkv,
    const float* __restrict__ cosT, const float* __restrict__ sinT,
    short* __restrict__ Qb, short* __restrict__ Kb) {
  int idx = blockIdx.x * 256 + threadIdx.x;   // B*S*40*64
  if (idx >= BB * SS * 40 * 64) return;
  int t = idx & 63;
  int hh = (idx >> 6) % 40;
  int bs = (idx >> 6) / 40;
  int s = bs & (SS - 1);
  int b = bs >> 11;
  const short* row = qkv + (long)bs * QKVN + hh * HD;
  float x1 = bf16_f32(row[t]);
  float x2 = bf16_f32(row[t + 64]);
  float c = cosT[(s << 6) + t], sn = sinT[(s << 6) + t];
  float o1 = x1 * c - x2 * sn;
  float o2 = x2 * c + x1 * sn;
  if (hh < 32) {
    const float sc = 0.08838834764831845f;  // 1/sqrt(128), folded into Q
    o1 *= sc; o2 *= sc;
    short* q = Qb + ((long)(b * NH + hh) * SS + s) * HD;
    q[t] = f32_bf16(o1); q[t + 64] = f32_bf16(o2);
  } else {
    short* k = Kb + ((long)(b * NKVH + (hh - 32)) * SS + s) * HD;
    k[t] = f32_bf16(o1); k[t + 64] = f32_bf16(o2);
  }
}

// ---------------------------------------------------------------- V transpose scatter
__global__ __launch_bounds__(256) void v_scatter_kernel(const short* __restrict__ qkv,
                                                        short* __restrict__ Vtb) {
  int bid = blockIdx.x;                 // 512 = B * NKVH * (SS/64)
  int s0 = (bid & 31) << 6;
  int kvh = (bid >> 5) & 7;
  int b = bid >> 8;
  const short* src = qkv + (long)(b * SS + s0) * QKVN + 5120 + kvh * HD;
  short* dst = Vtb + ((long)(b * NKVH + kvh) * HD) * SS + s0;
  int w = threadIdx.x >> 6, l = threadIdx.x & 63;
#pragma unroll
  for (int it = 0; it < 32; ++it) {
    int d = (it << 2) + w;
    dst[(long)d * SS + l] = src[(long)l * QKVN + d];
  }
}

// ---------------------------------------------------------------- GEMM 256x256 BK=64, free-running tile
// Round 14: six configs (blocks/CU, BK, FETCH, drain-0 vs counted) all pinned at
// MfmaUtil 33-35% -> the limiter is the PER-PHASE LOCKSTEP: [reads][barrier]
// [lgkmcnt(0)][MFMA][barrier] serializes LDS service (~300-400cy) against MFMA
// (155cy/SIMD) -> 155/500 ~ 31%. Those barriers guard NOTHING here: unlike m201
// (staging lands mid-tile), our buffer is stable for the entire tile. DELETE
// all intra-tile barriers + per-phase drains; software-pipeline A-frag reads one
// phase ahead (named regs, rule #20); compiler emits fine-grained lgkmcnt for
// plain ds_read->use deps (rule #18 is inline-asm-only). Tile boundaries keep
// round-13's verified discipline: top = STAGE(t+1) + vmcnt(8) + barrier (RAW);
// end = bare barrier (WAR). Never drain mid-loop. Swizzle slot^=row&7 both-sides
// (0 conflicts, round 9); square per-XCD supertiles (round 10, FETCH 352->180MB);
// plain __launch_bounds__(512) — NEVER pass min-waves (VGPR cap = 256/N; rounds
// 6/11 spilled catastrophically). NOTE acc=128 AGPR + ~112 VGPR ~ 240 unified ->
// 1 block/CU always (why round 12's "2 blocks" was null).
#define STAGE256(kt, bsel)                                                          \
  {                                                                                 \
    const long kbase_ = (long)(kt) << 6;                                            \
    _Pragma("unroll") for (int i_ = 0; i_ < 4; i_++) {                              \
      const int idx_ = tid + i_ * 512;                                              \
      const int row_ = idx_ >> 3, slot_ = idx_ & 7;                                 \
      const int ss_ = slot_ ^ (row_ & 7);                                           \
      async16(Ag0 + (long)row_ * K + kbase_ + ss_ * 8,                              \
              &Abuf[bsel][row_ * 64 + slot_ * 8]);                                  \
      async16(Bg0 + (long)row_ * K + kbase_ + ss_ * 8,                              \
              &Bbuf[bsel][row_ * 64 + slot_ * 8]);                                  \
    }                                                                               \
  }

// load A fragments for phase p into named frag pair
#define LDA(dst, p)                                                                 \
  {                                                                                 \
    _Pragma("unroll") for (int mi = 0; mi < 2; mi++)                                \
      _Pragma("unroll") for (int kk = 0; kk < 2; kk++)                              \
        dst[mi][kk] = *(const bf16x8*)&Ac[(((p) * 2 + mi) * 16 + l16) * 64 +        \
                                          ((((kk << 2) + quad) ^ xr) << 3)];        \
  }

// 16 MFMAs of phase p from named frag pair (no barriers, no drains)
#define MFMA16(src, p)                                                              \
  {                                                                                 \
    __builtin_amdgcn_s_setprio(1);                                                  \
    _Pragma("unroll") for (int mi = 0; mi < 2; mi++)                                \
      _Pragma("unroll") for (int nr = 0; nr < 4; nr++)                              \
        _Pragma("unroll") for (int kk = 0; kk < 2; kk++)                            \
          acc[(p) * 2 + mi][nr] = __builtin_amdgcn_mfma_f32_16x16x32_bf16(          \
              src[mi][kk], bfr[nr][kk], acc[(p) * 2 + mi][nr], 0, 0, 0);            \
    __builtin_amdgcn_s_setprio(0);                                                  \
  }

template <int STORE_BF16>
__global__ __launch_bounds__(512) void gemm256_kernel(const short* __restrict__ A,
    const short* __restrict__ B, void* __restrict__ Cv, int M, int N, int K, int gx) {
  __shared__ __align__(16) short Abuf[2][256 * 64];   // 64KB
  __shared__ __align__(16) short Bbuf[2][256 * 64];   // 64KB
  const int tid = threadIdx.x;
  const int lane = tid & 63, wave = tid >> 6;
  const int quad = lane >> 4, l16 = lane & 15;
  const int wm = wave >> 2;          // 0..1: M-half
  const int wn = wave & 3;           // 0..3: N-quarter
  const int xr = l16 & 7;            // read-side XOR key

  // Square per-XCD supertile decode (gy = 16 both call sites):
  const int bid = (int)blockIdx.x;
  const int xcd = bid & 7;
  const int i = bid >> 3;            // 0 .. nwg/8-1
  const int cpb = gx >> 2;           // patch cols (6 QKV, 4 O-proj)
  const int prow = i & 7;            // patch rows = 8 (gy/2)
  const int pcol = i >> 3;
  const int m0 = (((xcd >> 2) << 3) + prow) << 8;
  const int n0 = ((xcd & 3) * cpb + pcol) << 8;

  const short* Ag0 = A + (long)m0 * K;
  const short* Bg0 = B + (long)n0 * K;

  f32x4 acc[8][4];
#pragma unroll
  for (int mr = 0; mr < 8; mr++)
#pragma unroll
    for (int nr = 0; nr < 4; nr++) acc[mr][nr] = (f32x4){0.f, 0.f, 0.f, 0.f};

  const int nk = K >> 6;

  // prologue: stage tile 0 into buf0, drain once, align
  STAGE256(0, 0);
  asm volatile("s_waitcnt vmcnt(0)" ::: "memory");
  __builtin_amdgcn_sched_barrier(0);
  __builtin_amdgcn_s_barrier();

  int cur = 0;
#pragma unroll 1
  for (int kt = 0; kt < nk; ++kt) {
    // counted pipeline top: issue next tile, retire ONLY the current tile
    if (kt + 1 < nk) {
      if (cur == 0) { STAGE256(kt + 1, 1); } else { STAGE256(kt + 1, 0); }
      asm volatile("s_waitcnt vmcnt(8)" ::: "memory");   // STAGE(kt) done; kt+1 flies
    } else {
      asm volatile("s_waitcnt vmcnt(0)" ::: "memory");   // last tile: full drain
    }
    __builtin_amdgcn_sched_barrier(0);
    __builtin_amdgcn_s_barrier();                        // all waves: buf[cur] ready

    const short* Ac = &Abuf[cur][wm * 128 * 64];
    const short* Bc = &Bbuf[cur][wn * 64 * 64];

    // B fragments once per tile (8 x ds_read_b128), held in regs all 4 phases
    bf16x8 bfr[4][2];
#pragma unroll
    for (int nr = 0; nr < 4; nr++)
#pragma unroll
      for (int kk = 0; kk < 2; kk++)
        bfr[nr][kk] = *(const bf16x8*)&Bc[(nr * 16 + l16) * 64 +
                                          ((((kk << 2) + quad) ^ xr) << 3)];

    // free-running software-pipelined phases: reads of p+1 overlap MFMA of p;
    // compiler inserts fine-grained lgkmcnt on the register deps.
    bf16x8 aA[2][2], aB[2][2];
    LDA(aA, 0)
    LDA(aB, 1)
    MFMA16(aA, 0)
    LDA(aA, 2)
    MFMA16(aB, 1)
    LDA(aB, 3)
    MFMA16(aA, 2)
    MFMA16(aB, 3)

    // tile end: WAR barrier only (no drain) — next iter's STAGE overwrites
    // buf[cur] one flip later; all waves must be past their reads first.
    __builtin_amdgcn_s_barrier();
    cur ^= 1;
  }

  // epilogue
#pragma unroll
  for (int mr = 0; mr < 8; mr++)
#pragma unroll
    for (int nr = 0; nr < 4; nr++)
#pragma unroll
      for (int r = 0; r < 4; r++) {
        long row = m0 + wm * 128 + mr * 16 + quad * 4 + r;
        long col = n0 + wn * 64 + nr * 16 + l16;
        if (STORE_BF16)
          ((short*)Cv)[row * N + col] = f32_bf16(acc[mr][nr][r]);
        else
          ((float*)Cv)[row * N + col] = acc[mr][nr][r];
      }
}

// ---------------------------------------------------------------- flash attention v9 (proven round 9)
// Block-cooperative K+V LDS staging (4x traffic cut), uniform 34-step causal
// pairing, counted-vmcnt pipeline, XOR-swizzled tiles. Frozen.
#define PSS 72   // P LDS row stride (elements): 144B, 16B-multiple

#define STAGEK(j0_)                                                                 \
  {                                                                                 \
    _Pragma("unroll") for (int i_ = 0; i_ < 4; i_++) {                              \
      const int idx_ = tid + i_ * 256;                                              \
      const int r_ = idx_ >> 4, s_ = idx_ & 15;                                     \
      async16(Kb + (long)((j0_) + r_) * HD + ((s_ ^ (r_ & 7)) << 3),                \
              &Ks[r_ * 128 + (s_ << 3)]);                                           \
    }                                                                               \
  }

#define STAGEV(j0_)                                                                 \
  {                                                                                 \
    _Pragma("unroll") for (int i_ = 0; i_ < 4; i_++) {                              \
      const int idx_ = tid + i_ * 256;                                              \
      const int r_ = idx_ >> 3, s_ = idx_ & 7;                                      \
      async16(Vb + (long)r_ * SS + (j0_) + ((s_ ^ (r_ & 7)) << 3),                  \
              &Vs[r_ * 64 + (s_ << 3)]);                                            \
    }                                                                               \
  }

__global__ __launch_bounds__(256, 2) void flash_attn_kernel(const short* __restrict__ Q,
    const short* __restrict__ Kt, const short* __restrict__ Vt, short* __restrict__ O) {
  __shared__ __align__(16) short Ks[64 * 128];   // 16KB K tile (swizzled)
  __shared__ __align__(16) short Vs[128 * 64];   // 16KB V tile (swizzled, [d][key])
  __shared__ __align__(16) short Ps[4][32 * PSS];
  const int tid = threadIdx.x;
  const int wave = tid >> 6, lane = tid & 63;
  const int quad = lane >> 4, l16 = lane & 15;
  const int k7 = l16 & 7;                        // read-side XOR key

  // XCD co-location decode: 512 blocks; blocks sharing (b,kvh) share bid%8.
  const int flat = blockIdx.x;
  const int xcd = flat & 7;
  const int kk_ = flat >> 3;          // 0..63
  const int gsel = kk_ >> 5;          // 0..1
  const int jj = kk_ & 31;            // 0..31
  const int g = xcd * 2 + gsel;       // 0..15 = (b,kvh) group
  const int b = g >> 3, kvh = g & 7;
  const int h = (kvh << 2) + (jj >> 3);
  const int qb0 = jj & 7;

  const short* Kb = Kt + (long)(b * NKVH + kvh) * SS * HD;
  const short* Vb = Vt + (long)(b * NKVH + kvh) * HD * SS;
  short* Pw = &Ps[wave][0];

  // Two causal-complementary 128-row block-tiles: steps = (2qb+2)+(32-2qb) = 34.
#pragma unroll 1
  for (int half = 0; half < 2; half++) {
    const int qb = half ? (15 - qb0) : qb0;
    const int q0b = qb << 7;
    const int q0w = q0b + (wave << 5);
    const int nfull = q0w >> 6;            // this wave's last (masked) tile
    const int tsteps = (q0b >> 6) + 2;     // block-uniform step count

    const short* Qw = Q + ((long)(b * NH + h) * SS + q0w) * HD;
    bf16x8 qf[2][4];
#pragma unroll
    for (int i = 0; i < 2; i++)
#pragma unroll
      for (int kk = 0; kk < 4; kk++)
        qf[i][kk] = *(const bf16x8*)&Qw[(i * 16 + l16) * HD + kk * 32 + quad * 8];
    // drain Q loads so staging vmcnt counts stay exact
    asm volatile("s_waitcnt vmcnt(0)" ::: "memory");
    __builtin_amdgcn_sched_barrier(0);

    f32x4 oacc[2][8];
#pragma unroll
    for (int i = 0; i < 2; i++)
#pragma unroll
      for (int jo = 0; jo < 8; jo++) oacc[i][jo] = (f32x4){0.f, 0.f, 0.f, 0.f};
    float l_i[2][4];
#pragma unroll
    for (int i = 0; i < 2; i++)
#pragma unroll
      for (int r = 0; r < 4; r++) l_i[i][r] = 0.f;

    // prologue: stage K[0] then V[0]  (outstanding: K 4 oldest, V 4 newest)
    STAGEK(0)
    STAGEV(0)

#pragma unroll 1
    for (int t = 0; t < tsteps; t++) {
      const int j0 = t << 6;
      const bool active = (t <= nfull);
      const bool havenext = (t + 1 < tsteps);

      // top: retire K[t] (V[t] may still fly), align block
      asm volatile("s_waitcnt vmcnt(4)" ::: "memory");
      __builtin_amdgcn_sched_barrier(0);
      __builtin_amdgcn_s_barrier();
      __builtin_amdgcn_sched_barrier(0);

      f32x4 sc[2][4];
      if (active) {
        // QK from LDS K tile
        bf16x8 kf[16];
#pragma unroll
        for (int kk = 0; kk < 4; kk++)
#pragma unroll
          for (int j = 0; j < 4; j++)
            kf[kk * 4 + j] = *(const bf16x8*)&Ks[(j * 16 + l16) * 128 +
                                                 ((((kk << 2) + quad) ^ k7) << 3)];
#pragma unroll
        for (int i = 0; i < 2; i++)
#pragma unroll
          for (int j = 0; j < 4; j++) sc[i][j] = (f32x4){0.f, 0.f, 0.f, 0.f};
        __builtin_amdgcn_s_setprio(1);
#pragma unroll
        for (int kk = 0; kk < 4; kk++)
#pragma unroll
          for (int i = 0; i < 2; i++)
#pragma unroll
            for (int j = 0; j < 4; j++)
              sc[i][j] = __builtin_amdgcn_mfma_f32_16x16x32_bf16(
                  qf[i][kk], kf[kk * 4 + j], sc[i][j], 0, 0, 0);
        __builtin_amdgcn_s_setprio(0);
      }

      // all waves done reading Ks[t]
      __builtin_amdgcn_s_barrier();
      __builtin_amdgcn_sched_barrier(0);
      if (havenext) STAGEK(j0 + 64)   // hides under exp/P/PV

      if (active) {
        if (t == nfull) {
#pragma unroll
          for (int i = 0; i < 2; i++)
#pragma unroll
            for (int r = 0; r < 4; r++) {
              int row = q0w + i * 16 + quad * 4 + r;
#pragma unroll
              for (int j = 0; j < 4; j++) {
                int col = j0 + j * 16 + l16;
                if (col > row) sc[i][j][r] = -3.0e38f;
              }
            }
        }
        // p = exp(s); per-lane row-sum partials (max-free)
#pragma unroll
        for (int i = 0; i < 2; i++)
#pragma unroll
          for (int r = 0; r < 4; r++) {
            float ps = 0.f;
#pragma unroll
            for (int j = 0; j < 4; j++) {
              float p = __builtin_amdgcn_exp2f(sc[i][j][r] * LOG2E);
              sc[i][j][r] = p;
              ps += p;
            }
            l_i[i][r] += ps;
          }
        // P: C-layout -> per-wave LDS -> A-layout
#pragma unroll
        for (int i = 0; i < 2; i++)
#pragma unroll
          for (int j = 0; j < 4; j++)
#pragma unroll
            for (int r = 0; r < 4; r++)
              Pw[(i * 16 + quad * 4 + r) * PSS + j * 16 + l16] = f32_bf16(sc[i][j][r]);
      }

      // retire V[t] (K[t+1] may still fly), align block
      if (havenext) {
        asm volatile("s_waitcnt vmcnt(4)" ::: "memory");
      } else {
        asm volatile("s_waitcnt vmcnt(0)" ::: "memory");
      }
      __builtin_amdgcn_sched_barrier(0);
      __builtin_amdgcn_s_barrier();
      __builtin_amdgcn_sched_barrier(0);

      if (active) {
        asm volatile("s_waitcnt lgkmcnt(0)" ::: "memory");   // P writes landed
        bf16x8 ap[2][2];
#pragma unroll
        for (int kv = 0; kv < 2; kv++) {
          ap[kv][0] = *(const bf16x8*)&Pw[l16 * PSS + kv * 32 + quad * 8];
          ap[kv][1] = *(const bf16x8*)&Pw[(16 + l16) * PSS + kv * 32 + quad * 8];
        }
        // PV from LDS V tile
        __builtin_amdgcn_s_setprio(1);
#pragma unroll
        for (int jo = 0; jo < 8; jo++) {
          bf16x8 v0 = *(const bf16x8*)&Vs[(jo * 16 + l16) * 64 + ((quad ^ k7) << 3)];
          oacc[0][jo] = __builtin_amdgcn_mfma_f32_16x16x32_bf16(ap[0][0], v0,
                                                                oacc[0][jo], 0, 0, 0);
          oacc[1][jo] = __builtin_amdgcn_mfma_f32_16x16x32_bf16(ap[0][1], v0,
                                                                oacc[1][jo], 0, 0, 0);
        }
#pragma unroll
        for (int jo = 0; jo < 8; jo++) {
          bf16x8 v1 = *(const bf16x8*)&Vs[(jo * 16 + l16) * 64 +
                                          (((4 + quad) ^ k7) << 3)];
          oacc[0][jo] = __builtin_amdgcn_mfma_f32_16x16x32_bf16(ap[1][0], v1,
                                                                oacc[0][jo], 0, 0, 0);
          oacc[1][jo] = __builtin_amdgcn_mfma_f32_16x16x32_bf16(ap[1][1], v1,
                                                                oacc[1][jo], 0, 0, 0);
        }
        __builtin_amdgcn_s_setprio(0);
      }

      // all waves done reading Vs[t]
      __builtin_amdgcn_s_barrier();
      __builtin_amdgcn_sched_barrier(0);
      if (havenext) STAGEV(j0 + 64)   // hides under next QK
    }

    // epilogue: reduce l across the 16 lanes of each quad (once), store
    short* Ob = O + (long)(b * SS + q0w) * DD + h * HD;
#pragma unroll
    for (int i = 0; i < 2; i++)
#pragma unroll
      for (int r = 0; r < 4; r++) {
        float s = l_i[i][r];
        s += __shfl_xor(s, 1, 64);
        s += __shfl_xor(s, 2, 64);
        s += __shfl_xor(s, 4, 64);
        s += __shfl_xor(s, 8, 64);
        float inv = 1.0f / s;
        int row = i * 16 + quad * 4 + r;
#pragma unroll
        for (int jo = 0; jo < 8; jo++)
          Ob[(long)row * DD + jo * 16 + l16] = f32_bf16(oacc[i][jo][r] * inv);
      }
  }
}

// ---------------------------------------------------------------- launch
extern "C" void kernel_launch(void* const* d_in, const int* in_sizes, int n_in,
                              void* d_out, int out_size, void* d_ws, size_t ws_size,
                              hipStream_t stream) {
  (void)in_sizes; (void)n_in; (void)out_size; (void)ws_size;
  const float* x    = (const float*)d_in[0];
  const float* Wqkv = (const float*)d_in[1];
  const float* Wo   = (const float*)d_in[2];
  char* ws = (char*)d_ws;
  short* xb    = (short*)(ws + 0);            // x bf16 (33.5MB); reused as attn out
  short* wqkvb = (short*)(ws + 33554432);     // Wqkv bf16 (50.3MB)
  short* qkvb  = (short*)(ws + 83886080);     // qkv (50.3MB); reused as Wo bf16
  short* Qb    = (short*)(ws + 134217728);    // 33.5MB
  short* Kb    = (short*)(ws + 167772160);    // 8.4MB
  short* Vtb   = (short*)(ws + 176160768);    // 8.4MB
  float* cosT  = (float*)(ws + 184549376);    // 0.5MB
  float* sinT  = (float*)(ws + 185073664);    // 0.5MB
  short* wob   = qkvb;
  short* attnb = xb;

  cast_bf16_kernel<<<16384, 256, 0, stream>>>(x, xb, 4194304);
  cast_bf16_kernel<<<24576, 256, 0, stream>>>(Wqkv, wqkvb, 6291456);
  gemm256_kernel<1><<<dim3((QKVN / 256) * (MROWS / 256)), 512, 0, stream>>>(
      xb, wqkvb, (void*)qkvb, MROWS, QKVN, DD, QKVN / 256);
  rope_tables_kernel<<<512, 256, 0, stream>>>(cosT, sinT);
  rope_scatter_kernel<<<40960, 256, 0, stream>>>(qkvb, cosT, sinT, Qb, Kb);
  v_scatter_kernel<<<512, 256, 0, stream>>>(qkvb, Vtb);
  cast_bf16_kernel<<<16384, 256, 0, stream>>>(Wo, wob, 4194304);   // overwrites qkvb (dead)
  flash_attn_kernel<<<512, 256, 0, stream>>>(Qb, Kb, Vtb, attnb);
  gemm256_kernel<0><<<dim3((DD / 256) * (MROWS / 256)), 512, 0, stream>>>(
      attnb, wob, d_out, MROWS, DD, DD, DD / 256);
}

// Round 15
// 719.284 us; speedup vs baseline: 1.0353x; 1.0060x over previous
//
#include <hip/hip_runtime.h>
#include <stdint.h>

// Problem constants
#define BB 2
#define SS 2048
#define DD 4096
#define NH 32
#define NKVH 8
#define HD 128
#define QKVN 6144          // (32 + 2*8) * 128
#define MROWS (BB * SS)    // 4096
#define LOG2E 1.4426950408889634f

typedef short bf16x8 __attribute__((ext_vector_type(8)));   // 8 bf16 in 4 VGPRs
typedef float f32x4 __attribute__((ext_vector_type(4)));

__device__ __forceinline__ short f32_bf16(float f) {
  union { float f; unsigned u; } c; c.f = f;
  unsigned r = (c.u + 0x7fffu + ((c.u >> 16) & 1u)) >> 16;   // RNE
  return (short)r;
}
__device__ __forceinline__ float bf16_f32(short h) {
  union { unsigned u; float f; } c; c.u = ((unsigned)(unsigned short)h) << 16;
  return c.f;
}

// async global->LDS, 16B per lane. LDS dest must be wave-uniform base + lane*16.
__device__ __forceinline__ void async16(const void* g, void* l) {
  __builtin_amdgcn_global_load_lds(
      (const __attribute__((address_space(1))) unsigned int*)(uintptr_t)g,
      (__attribute__((address_space(3))) unsigned int*)(uintptr_t)l,
      16, 0, 0);
}

// ---------------------------------------------------------------- cast f32 -> bf16
__global__ __launch_bounds__(256) void cast_bf16_kernel(const float* __restrict__ in,
                                                        short* __restrict__ out, int n4) {
  int i = blockIdx.x * 256 + threadIdx.x;
  if (i >= n4) return;
  float4 v = ((const float4*)in)[i];
  short4 o;
  o.x = f32_bf16(v.x); o.y = f32_bf16(v.y); o.z = f32_bf16(v.z); o.w = f32_bf16(v.w);
  ((short4*)out)[i] = o;
}

// ---------------------------------------------------------------- rope tables
__global__ __launch_bounds__(256) void rope_tables_kernel(float* __restrict__ cosT,
                                                          float* __restrict__ sinT) {
  int idx = blockIdx.x * 256 + threadIdx.x;   // S*64
  if (idx >= SS * 64) return;
  int s = idx >> 6, t = idx & 63;
  float invf = exp2f(-(float)t * (18.931568569324174f / 64.0f));  // log2(500000)/64
  float fr = (float)s * invf;
  float sv, cv;
  sincosf(fr, &sv, &cv);
  cosT[idx] = cv;
  sinT[idx] = sv;
}

// ---------------------------------------------------------------- rope + scatter (Q,K only)
__global__ __launch_bounds__(256) void rope_scatter_kernel(const short* __restrict__ qkv,
    const float* __restrict__ cosT, const float* __restrict__ sinT,
    short* __restrict__ Qb, short* __restrict__ Kb) {
  int idx = blockIdx.x * 256 + threadIdx.x;   // B*S*40*64
  if (idx >= BB * SS * 40 * 64) return;
  int t = idx & 63;
  int hh = (idx >> 6) % 40;
  int bs = (idx >> 6) / 40;
  int s = bs & (SS - 1);
  int b = bs >> 11;
  const short* row = qkv + (long)bs * QKVN + hh * HD;
  float x1 = bf16_f32(row[t]);
  float x2 = bf16_f32(row[t + 64]);
  float c = cosT[(s << 6) + t], sn = sinT[(s << 6) + t];
  float o1 = x1 * c - x2 * sn;
  float o2 = x2 * c + x1 * sn;
  if (hh < 32) {
    const float sc = 0.08838834764831845f;  // 1/sqrt(128), folded into Q
    o1 *= sc; o2 *= sc;
    short* q = Qb + ((long)(b * NH + hh) * SS + s) * HD;
    q[t] = f32_bf16(o1); q[t + 64] = f32_bf16(o2);
  } else {
    short* k = Kb + ((long)(b * NKVH + (hh - 32)) * SS + s) * HD;
    k[t] = f32_bf16(o1); k[t + 64] = f32_bf16(o2);
  }
}

// ---------------------------------------------------------------- V transpose scatter
__global__ __launch_bounds__(256) void v_scatter_kernel(const short* __restrict__ qkv,
                                                        short* __restrict__ Vtb) {
  int bid = blockIdx.x;                 // 512 = B * NKVH * (SS/64)
  int s0 = (bid & 31) << 6;
  int kvh = (bid >> 5) & 7;
  int b = bid >> 8;
  const short* src = qkv + (long)(b * SS + s0) * QKVN + 5120 + kvh * HD;
  short* dst = Vtb + ((long)(b * NKVH + kvh) * HD) * SS + s0;
  int w = threadIdx.x >> 6, l = threadIdx.x & 63;
#pragma unroll
  for (int it = 0; it < 32; ++it) {
    int d = (it << 2) + w;
    dst[(long)d * SS + l] = src[(long)l * QKVN + d];
  }
}

// ---------------------------------------------------------------- GEMM 256x256 BK=64, per-phase stage interleave
// Round 15: seven configs all pinned at MfmaUtil 33-35%. The ONE documented
// untested lever is m196's: the 8-phase gain comes from the FINE per-phase
// interleave of {ds_read || stage-issue || MFMA} — coarse stage-at-top variants
// (rounds 13/14) are exactly m196's null band. This round spreads the staging:
// one half-tile (2 global_load_lds/thread) into EACH phase (ph0->Ah0, ph1->Ah1,
// ph2->Bh0, ph3->Bh1 of tile t+1), phase body otherwise identical to the m201
// template (reads; stage; barrier; lgkmcnt(0); setprio; 16 MFMA; setprio;
// barrier). Tile boundary: vmcnt(0) — here an EXACT counted wait (only the 4
// stages of t+1 are outstanding; all 4 halves are needed at t+1 phase 0 since
// B-frags span both B-halves and A-quad0 spans both A-halves, so no looser
// counted wait is safe with 2 buffers). WAR: buf^1's prior readers passed the
// previous boundary barrier. Swizzle slot^=row&7 both-sides (0 conflicts);
// square per-XCD supertiles (FETCH 352->180MB); plain __launch_bounds__(512)
// — NEVER pass min-waves (VGPR cap = 256/N; rounds 6/11 spilled).
#define STAGEH_A(kt, bsel, h)                                                       \
  {                                                                                 \
    const long kb_ = (long)(kt) << 6;                                               \
    _Pragma("unroll") for (int j_ = 0; j_ < 2; j_++) {                              \
      const int idx_ = tid + j_ * 512;                                              \
      const int r_ = (idx_ >> 3) + (h) * 128;                                       \
      const int s_ = idx_ & 7;                                                      \
      const int ss_ = s_ ^ (r_ & 7);                                                \
      async16(Ag0 + (long)r_ * K + kb_ + ss_ * 8, &Abuf[bsel][r_ * 64 + s_ * 8]);   \
    }                                                                               \
  }

#define STAGEH_B(kt, bsel, h)                                                       \
  {                                                                                 \
    const long kb_ = (long)(kt) << 6;                                               \
    _Pragma("unroll") for (int j_ = 0; j_ < 2; j_++) {                              \
      const int idx_ = tid + j_ * 512;                                              \
      const int r_ = (idx_ >> 3) + (h) * 128;                                       \
      const int s_ = idx_ & 7;                                                      \
      const int ss_ = s_ ^ (r_ & 7);                                                \
      async16(Bg0 + (long)r_ * K + kb_ + ss_ * 8, &Bbuf[bsel][r_ * 64 + s_ * 8]);   \
    }                                                                               \
  }

// load A fragments for phase p into named frag pair
#define LDA(dst, p)                                                                 \
  {                                                                                 \
    _Pragma("unroll") for (int mi = 0; mi < 2; mi++)                                \
      _Pragma("unroll") for (int kk = 0; kk < 2; kk++)                              \
        dst[mi][kk] = *(const bf16x8*)&Ac[(((p) * 2 + mi) * 16 + l16) * 64 +        \
                                          ((((kk << 2) + quad) ^ xr) << 3)];        \
  }

// phase tail: barrier-aligned MFMA cluster (template-faithful)
#define PHTAIL(src, p)                                                              \
  {                                                                                 \
    __builtin_amdgcn_s_barrier();                                                   \
    asm volatile("s_waitcnt lgkmcnt(0)" ::: "memory");                              \
    __builtin_amdgcn_sched_barrier(0);                                              \
    __builtin_amdgcn_s_setprio(1);                                                  \
    _Pragma("unroll") for (int mi = 0; mi < 2; mi++)                                \
      _Pragma("unroll") for (int nr = 0; nr < 4; nr++)                              \
        _Pragma("unroll") for (int kk = 0; kk < 2; kk++)                            \
          acc[(p) * 2 + mi][nr] = __builtin_amdgcn_mfma_f32_16x16x32_bf16(          \
              src[mi][kk], bfr[nr][kk], acc[(p) * 2 + mi][nr], 0, 0, 0);            \
    __builtin_amdgcn_s_setprio(0);                                                  \
    __builtin_amdgcn_s_barrier();                                                   \
  }

template <int STORE_BF16>
__global__ __launch_bounds__(512) void gemm256_kernel(const short* __restrict__ A,
    const short* __restrict__ B, void* __restrict__ Cv, int M, int N, int K, int gx) {
  __shared__ __align__(16) short Abuf[2][256 * 64];   // 64KB
  __shared__ __align__(16) short Bbuf[2][256 * 64];   // 64KB
  const int tid = threadIdx.x;
  const int lane = tid & 63, wave = tid >> 6;
  const int quad = lane >> 4, l16 = lane & 15;
  const int wm = wave >> 2;          // 0..1: M-half
  const int wn = wave & 3;           // 0..3: N-quarter
  const int xr = l16 & 7;            // read-side XOR key

  // Square per-XCD supertile decode (gy = 16 both call sites):
  const int bid = (int)blockIdx.x;
  const int xcd = bid & 7;
  const int i = bid >> 3;            // 0 .. nwg/8-1
  const int cpb = gx >> 2;           // patch cols (6 QKV, 4 O-proj)
  const int prow = i & 7;            // patch rows = 8 (gy/2)
  const int pcol = i >> 3;
  const int m0 = (((xcd >> 2) << 3) + prow) << 8;
  const int n0 = ((xcd & 3) * cpb + pcol) << 8;

  const short* Ag0 = A + (long)m0 * K;
  const short* Bg0 = B + (long)n0 * K;

  f32x4 acc[8][4];
#pragma unroll
  for (int mr = 0; mr < 8; mr++)
#pragma unroll
    for (int nr = 0; nr < 4; nr++) acc[mr][nr] = (f32x4){0.f, 0.f, 0.f, 0.f};

  const int nk = K >> 6;

  // prologue: stage all 4 halves of tile 0 into buf0, exact drain, align
  STAGEH_A(0, 0, 0)
  STAGEH_A(0, 0, 1)
  STAGEH_B(0, 0, 0)
  STAGEH_B(0, 0, 1)
  asm volatile("s_waitcnt vmcnt(0)" ::: "memory");
  __builtin_amdgcn_sched_barrier(0);
  __builtin_amdgcn_s_barrier();

  int cur = 0;
#pragma unroll 1
  for (int kt = 0; kt < nk; ++kt) {
    const short* Ac = &Abuf[cur][wm * 128 * 64];
    const short* Bc = &Bbuf[cur][wn * 64 * 64];
    const int nb = cur ^ 1;
    const bool pf = (kt + 1 < nk);

    bf16x8 afr[2][2];
    bf16x8 bfr[4][2];

    // ---- phase 0: B-frags(8) + A-quad0(4); stage Ah0(t+1)
#pragma unroll
    for (int nr = 0; nr < 4; nr++)
#pragma unroll
      for (int kk = 0; kk < 2; kk++)
        bfr[nr][kk] = *(const bf16x8*)&Bc[(nr * 16 + l16) * 64 +
                                          ((((kk << 2) + quad) ^ xr) << 3)];
    LDA(afr, 0)
    if (pf) { STAGEH_A(kt + 1, nb, 0) }
    PHTAIL(afr, 0)

    // ---- phase 1: A-quad1; stage Ah1(t+1)
    LDA(afr, 1)
    if (pf) { STAGEH_A(kt + 1, nb, 1) }
    PHTAIL(afr, 1)

    // ---- phase 2: A-quad2; stage Bh0(t+1)
    LDA(afr, 2)
    if (pf) { STAGEH_B(kt + 1, nb, 0) }
    PHTAIL(afr, 2)

    // ---- phase 3: A-quad3; stage Bh1(t+1)
    LDA(afr, 3)
    if (pf) { STAGEH_B(kt + 1, nb, 1) }
    PHTAIL(afr, 3)

    // tile boundary: exact counted drain (only t+1's 4 stages outstanding),
    // then WAR/RAW barrier; flip buffers.
    asm volatile("s_waitcnt vmcnt(0)" ::: "memory");
    __builtin_amdgcn_sched_barrier(0);
    __builtin_amdgcn_s_barrier();
    cur ^= 1;
  }

  // epilogue
#pragma unroll
  for (int mr = 0; mr < 8; mr++)
#pragma unroll
    for (int nr = 0; nr < 4; nr++)
#pragma unroll
      for (int r = 0; r < 4; r++) {
        long row = m0 + wm * 128 + mr * 16 + quad * 4 + r;
        long col = n0 + wn * 64 + nr * 16 + l16;
        if (STORE_BF16)
          ((short*)Cv)[row * N + col] = f32_bf16(acc[mr][nr][r]);
        else
          ((float*)Cv)[row * N + col] = acc[mr][nr][r];
      }
}

// ---------------------------------------------------------------- flash attention v9 (proven round 9)
// Block-cooperative K+V LDS staging (4x traffic cut), uniform 34-step causal
// pairing, counted-vmcnt pipeline, XOR-swizzled tiles. Frozen.
#define PSS 72   // P LDS row stride (elements): 144B, 16B-multiple

#define STAGEK(j0_)                                                                 \
  {                                                                                 \
    _Pragma("unroll") for (int i_ = 0; i_ < 4; i_++) {                              \
      const int idx_ = tid + i_ * 256;                                              \
      const int r_ = idx_ >> 4, s_ = idx_ & 15;                                     \
      async16(Kb + (long)((j0_) + r_) * HD + ((s_ ^ (r_ & 7)) << 3),                \
              &Ks[r_ * 128 + (s_ << 3)]);                                           \
    }                                                                               \
  }

#define STAGEV(j0_)                                                                 \
  {                                                                                 \
    _Pragma("unroll") for (int i_ = 0; i_ < 4; i_++) {                              \
      const int idx_ = tid + i_ * 256;                                              \
      const int r_ = idx_ >> 3, s_ = idx_ & 7;                                      \
      async16(Vb + (long)r_ * SS + (j0_) + ((s_ ^ (r_ & 7)) << 3),                  \
              &Vs[r_ * 64 + (s_ << 3)]);                                            \
    }                                                                               \
  }

__global__ __launch_bounds__(256, 2) void flash_attn_kernel(const short* __restrict__ Q,
    const short* __restrict__ Kt, const short* __restrict__ Vt, short* __restrict__ O) {
  __shared__ __align__(16) short Ks[64 * 128];   // 16KB K tile (swizzled)
  __shared__ __align__(16) short Vs[128 * 64];   // 16KB V tile (swizzled, [d][key])
  __shared__ __align__(16) short Ps[4][32 * PSS];
  const int tid = threadIdx.x;
  const int wave = tid >> 6, lane = tid & 63;
  const int quad = lane >> 4, l16 = lane & 15;
  const int k7 = l16 & 7;                        // read-side XOR key

  // XCD co-location decode: 512 blocks; blocks sharing (b,kvh) share bid%8.
  const int flat = blockIdx.x;
  const int xcd = flat & 7;
  const int kk_ = flat >> 3;          // 0..63
  const int gsel = kk_ >> 5;          // 0..1
  const int jj = kk_ & 31;            // 0..31
  const int g = xcd * 2 + gsel;       // 0..15 = (b,kvh) group
  const int b = g >> 3, kvh = g & 7;
  const int h = (kvh << 2) + (jj >> 3);
  const int qb0 = jj & 7;

  const short* Kb = Kt + (long)(b * NKVH + kvh) * SS * HD;
  const short* Vb = Vt + (long)(b * NKVH + kvh) * HD * SS;
  short* Pw = &Ps[wave][0];

  // Two causal-complementary 128-row block-tiles: steps = (2qb+2)+(32-2qb) = 34.
#pragma unroll 1
  for (int half = 0; half < 2; half++) {
    const int qb = half ? (15 - qb0) : qb0;
    const int q0b = qb << 7;
    const int q0w = q0b + (wave << 5);
    const int nfull = q0w >> 6;            // this wave's last (masked) tile
    const int tsteps = (q0b >> 6) + 2;     // block-uniform step count

    const short* Qw = Q + ((long)(b * NH + h) * SS + q0w) * HD;
    bf16x8 qf[2][4];
#pragma unroll
    for (int i = 0; i < 2; i++)
#pragma unroll
      for (int kk = 0; kk < 4; kk++)
        qf[i][kk] = *(const bf16x8*)&Qw[(i * 16 + l16) * HD + kk * 32 + quad * 8];
    // drain Q loads so staging vmcnt counts stay exact
    asm volatile("s_waitcnt vmcnt(0)" ::: "memory");
    __builtin_amdgcn_sched_barrier(0);

    f32x4 oacc[2][8];
#pragma unroll
    for (int i = 0; i < 2; i++)
#pragma unroll
      for (int jo = 0; jo < 8; jo++) oacc[i][jo] = (f32x4){0.f, 0.f, 0.f, 0.f};
    float l_i[2][4];
#pragma unroll
    for (int i = 0; i < 2; i++)
#pragma unroll
      for (int r = 0; r < 4; r++) l_i[i][r] = 0.f;

    // prologue: stage K[0] then V[0]  (outstanding: K 4 oldest, V 4 newest)
    STAGEK(0)
    STAGEV(0)

#pragma unroll 1
    for (int t = 0; t < tsteps; t++) {
      const int j0 = t << 6;
      const bool active = (t <= nfull);
      const bool havenext = (t + 1 < tsteps);

      // top: retire K[t] (V[t] may still fly), align block
      asm volatile("s_waitcnt vmcnt(4)" ::: "memory");
      __builtin_amdgcn_sched_barrier(0);
      __builtin_amdgcn_s_barrier();
      __builtin_amdgcn_sched_barrier(0);

      f32x4 sc[2][4];
      if (active) {
        // QK from LDS K tile
        bf16x8 kf[16];
#pragma unroll
        for (int kk = 0; kk < 4; kk++)
#pragma unroll
          for (int j = 0; j < 4; j++)
            kf[kk * 4 + j] = *(const bf16x8*)&Ks[(j * 16 + l16) * 128 +
                                                 ((((kk << 2) + quad) ^ k7) << 3)];
#pragma unroll
        for (int i = 0; i < 2; i++)
#pragma unroll
          for (int j = 0; j < 4; j++) sc[i][j] = (f32x4){0.f, 0.f, 0.f, 0.f};
        __builtin_amdgcn_s_setprio(1);
#pragma unroll
        for (int kk = 0; kk < 4; kk++)
#pragma unroll
          for (int i = 0; i < 2; i++)
#pragma unroll
            for (int j = 0; j < 4; j++)
              sc[i][j] = __builtin_amdgcn_mfma_f32_16x16x32_bf16(
                  qf[i][kk], kf[kk * 4 + j], sc[i][j], 0, 0, 0);
        __builtin_amdgcn_s_setprio(0);
      }

      // all waves done reading Ks[t]
      __builtin_amdgcn_s_barrier();
      __builtin_amdgcn_sched_barrier(0);
      if (havenext) STAGEK(j0 + 64)   // hides under exp/P/PV

      if (active) {
        if (t == nfull) {
#pragma unroll
          for (int i = 0; i < 2; i++)
#pragma unroll
            for (int r = 0; r < 4; r++) {
              int row = q0w + i * 16 + quad * 4 + r;
#pragma unroll
              for (int j = 0; j < 4; j++) {
                int col = j0 + j * 16 + l16;
                if (col > row) sc[i][j][r] = -3.0e38f;
              }
            }
        }
        // p = exp(s); per-lane row-sum partials (max-free)
#pragma unroll
        for (int i = 0; i < 2; i++)
#pragma unroll
          for (int r = 0; r < 4; r++) {
            float ps = 0.f;
#pragma unroll
            for (int j = 0; j < 4; j++) {
              float p = __builtin_amdgcn_exp2f(sc[i][j][r] * LOG2E);
              sc[i][j][r] = p;
              ps += p;
            }
            l_i[i][r] += ps;
          }
        // P: C-layout -> per-wave LDS -> A-layout
#pragma unroll
        for (int i = 0; i < 2; i++)
#pragma unroll
          for (int j = 0; j < 4; j++)
#pragma unroll
            for (int r = 0; r < 4; r++)
              Pw[(i * 16 + quad * 4 + r) * PSS + j * 16 + l16] = f32_bf16(sc[i][j][r]);
      }

      // retire V[t] (K[t+1] may still fly), align block
      if (havenext) {
        asm volatile("s_waitcnt vmcnt(4)" ::: "memory");
      } else {
        asm volatile("s_waitcnt vmcnt(0)" ::: "memory");
      }
      __builtin_amdgcn_sched_barrier(0);
      __builtin_amdgcn_s_barrier();
      __builtin_amdgcn_sched_barrier(0);

      if (active) {
        asm volatile("s_waitcnt lgkmcnt(0)" ::: "memory");   // P writes landed
        bf16x8 ap[2][2];
#pragma unroll
        for (int kv = 0; kv < 2; kv++) {
          ap[kv][0] = *(const bf16x8*)&Pw[l16 * PSS + kv * 32 + quad * 8];
          ap[kv][1] = *(const bf16x8*)&Pw[(16 + l16) * PSS + kv * 32 + quad * 8];
        }
        // PV from LDS V tile
        __builtin_amdgcn_s_setprio(1);
#pragma unroll
        for (int jo = 0; jo < 8; jo++) {
          bf16x8 v0 = *(const bf16x8*)&Vs[(jo * 16 + l16) * 64 + ((quad ^ k7) << 3)];
          oacc[0][jo] = __builtin_amdgcn_mfma_f32_16x16x32_bf16(ap[0][0], v0,
                                                                oacc[0][jo], 0, 0, 0);
          oacc[1][jo] = __builtin_amdgcn_mfma_f32_16x16x32_bf16(ap[0][1], v0,
                                                                oacc[1][jo], 0, 0, 0);
        }
#pragma unroll
        for (int jo = 0; jo < 8; jo++) {
          bf16x8 v1 = *(const bf16x8*)&Vs[(jo * 16 + l16) * 64 +
                                          (((4 + quad) ^ k7) << 3)];
          oacc[0][jo] = __builtin_amdgcn_mfma_f32_16x16x32_bf16(ap[1][0], v1,
                                                                oacc[0][jo], 0, 0, 0);
          oacc[1][jo] = __builtin_amdgcn_mfma_f32_16x16x32_bf16(ap[1][1], v1,
                                                                oacc[1][jo], 0, 0, 0);
        }
        __builtin_amdgcn_s_setprio(0);
      }

      // all waves done reading Vs[t]
      __builtin_amdgcn_s_barrier();
      __builtin_amdgcn_sched_barrier(0);
      if (havenext) STAGEV(j0 + 64)   // hides under next QK
    }

    // epilogue: reduce l across the 16 lanes of each quad (once), store
    short* Ob = O + (long)(b * SS + q0w) * DD + h * HD;
#pragma unroll
    for (int i = 0; i < 2; i++)
#pragma unroll
      for (int r = 0; r < 4; r++) {
        float s = l_i[i][r];
        s += __shfl_xor(s, 1, 64);
        s += __shfl_xor(s, 2, 64);
        s += __shfl_xor(s, 4, 64);
        s += __shfl_xor(s, 8, 64);
        float inv = 1.0f / s;
        int row = i * 16 + quad * 4 + r;
#pragma unroll
        for (int jo = 0; jo < 8; jo++)
          Ob[(long)row * DD + jo * 16 + l16] = f32_bf16(oacc[i][jo][r] * inv);
      }
  }
}

// ---------------------------------------------------------------- launch
extern "C" void kernel_launch(void* const* d_in, const int* in_sizes, int n_in,
                              void* d_out, int out_size, void* d_ws, size_t ws_size,
                              hipStream_t stream) {
  (void)in_sizes; (void)n_in; (void)out_size; (void)ws_size;
  const float* x    = (const float*)d_in[0];
  const float* Wqkv = (const float*)d_in[1];
  const float* Wo   = (const float*)d_in[2];
  char* ws = (char*)d_ws;
  short* xb    = (short*)(ws + 0);            // x bf16 (33.5MB); reused as attn out
  short* wqkvb = (short*)(ws + 33554432);     // Wqkv bf16 (50.3MB)
  short* qkvb  = (short*)(ws + 83886080);     // qkv (50.3MB); reused as Wo bf16
  short* Qb    = (short*)(ws + 134217728);    // 33.5MB
  short* Kb    = (short*)(ws + 167772160);    // 8.4MB
  short* Vtb   = (short*)(ws + 176160768);    // 8.4MB
  float* cosT  = (float*)(ws + 184549376);    // 0.5MB
  float* sinT  = (float*)(ws + 185073664);    // 0.5MB
  short* wob   = qkvb;
  short* attnb = xb;

  cast_bf16_kernel<<<16384, 256, 0, stream>>>(x, xb, 4194304);
  cast_bf16_kernel<<<24576, 256, 0, stream>>>(Wqkv, wqkvb, 6291456);
  gemm256_kernel<1><<<dim3((QKVN / 256) * (MROWS / 256)), 512, 0, stream>>>(
      xb, wqkvb, (void*)qkvb, MROWS, QKVN, DD, QKVN / 256);
  rope_tables_kernel<<<512, 256, 0, stream>>>(cosT, sinT);
  rope_scatter_kernel<<<40960, 256, 0, stream>>>(qkvb, cosT, sinT, Qb, Kb);
  v_scatter_kernel<<<512, 256, 0, stream>>>(qkvb, Vtb);
  cast_bf16_kernel<<<16384, 256, 0, stream>>>(Wo, wob, 4194304);   // overwrites qkvb (dead)
  flash_attn_kernel<<<512, 256, 0, stream>>>(Qb, Kb, Vtb, attnb);
  gemm256_kernel<0><<<dim3((DD / 256) * (MROWS / 256)), 512, 0, stream>>>(
      attnb, wob, d_out, MROWS, DD, DD, DD / 256);
}

// Round 16
// 708.094 us; speedup vs baseline: 1.0516x; 1.0158x over previous
//
#include <hip/hip_runtime.h>
#include <stdint.h>

// Problem constants
#define BB 2
#define SS 2048
#define DD 4096
#define NH 32
#define NKVH 8
#define HD 128
#define QKVN 6144          // (32 + 2*8) * 128
#define MROWS (BB * SS)    // 4096
#define LOG2E 1.4426950408889634f

typedef short bf16x8 __attribute__((ext_vector_type(8)));   // 8 bf16 in 4 VGPRs
typedef float f32x4 __attribute__((ext_vector_type(4)));

__device__ __forceinline__ short f32_bf16(float f) {
  union { float f; unsigned u; } c; c.f = f;
  unsigned r = (c.u + 0x7fffu + ((c.u >> 16) & 1u)) >> 16;   // RNE
  return (short)r;
}
__device__ __forceinline__ float bf16_f32(short h) {
  union { unsigned u; float f; } c; c.u = ((unsigned)(unsigned short)h) << 16;
  return c.f;
}

// async global->LDS, 16B per lane. LDS dest must be wave-uniform base + lane*16.
__device__ __forceinline__ void async16(const void* g, void* l) {
  __builtin_amdgcn_global_load_lds(
      (const __attribute__((address_space(1))) unsigned int*)(uintptr_t)g,
      (__attribute__((address_space(3))) unsigned int*)(uintptr_t)l,
      16, 0, 0);
}

// ---------------------------------------------------------------- cast f32 -> bf16
__global__ __launch_bounds__(256) void cast_bf16_kernel(const float* __restrict__ in,
                                                        short* __restrict__ out, int n4) {
  int i = blockIdx.x * 256 + threadIdx.x;
  if (i >= n4) return;
  float4 v = ((const float4*)in)[i];
  short4 o;
  o.x = f32_bf16(v.x); o.y = f32_bf16(v.y); o.z = f32_bf16(v.z); o.w = f32_bf16(v.w);
  ((short4*)out)[i] = o;
}

// ---------------------------------------------------------------- rope tables
__global__ __launch_bounds__(256) void rope_tables_kernel(float* __restrict__ cosT,
                                                          float* __restrict__ sinT) {
  int idx = blockIdx.x * 256 + threadIdx.x;   // S*64
  if (idx >= SS * 64) return;
  int s = idx >> 6, t = idx & 63;
  float invf = exp2f(-(float)t * (18.931568569324174f / 64.0f));  // log2(500000)/64
  float fr = (float)s * invf;
  float sv, cv;
  sincosf(fr, &sv, &cv);
  cosT[idx] = cv;
  sinT[idx] = sv;
}

// ---------------------------------------------------------------- rope + scatter (Q,K only)
// Round 16: vectorized x4 (G13). Each thread handles 4 consecutive t values of
// one (bs,hh) row: short4 loads of both rotation halves, float4 table loads,
// short4 stores. 8B/lane coalesced (16 lanes cover one 128B half-row). Grid /4.
__global__ __launch_bounds__(256) void rope_scatter_kernel(const short* __restrict__ qkv,
    const float* __restrict__ cosT, const float* __restrict__ sinT,
    short* __restrict__ Qb, short* __restrict__ Kb) {
  int idx = blockIdx.x * 256 + threadIdx.x;   // B*S*40*16
  if (idx >= BB * SS * 40 * 16) return;
  int t0 = (idx & 15) << 2;                   // 0,4,...,60
  int hh = (idx >> 4) % 40;
  int bs = (idx >> 4) / 40;
  int s = bs & (SS - 1);
  int b = bs >> 11;
  const short* row = qkv + (long)bs * QKVN + hh * HD;
  short4 x1 = *(const short4*)&row[t0];
  short4 x2 = *(const short4*)&row[t0 + 64];
  float4 c4 = *(const float4*)&cosT[(s << 6) + t0];
  float4 s4 = *(const float4*)&sinT[(s << 6) + t0];
  const short* x1e = (const short*)&x1;
  const short* x2e = (const short*)&x2;
  const float* ce = (const float*)&c4;
  const float* se = (const float*)&s4;
  short4 o1, o2;
  short* o1e = (short*)&o1;
  short* o2e = (short*)&o2;
  const bool isq = (hh < 32);
  const float sc = isq ? 0.08838834764831845f : 1.0f;  // 1/sqrt(128) folded into Q
#pragma unroll
  for (int j = 0; j < 4; j++) {
    float a = bf16_f32(x1e[j]);
    float d = bf16_f32(x2e[j]);
    float v1 = (a * ce[j] - d * se[j]) * sc;
    float v2 = (d * ce[j] + a * se[j]) * sc;
    o1e[j] = f32_bf16(v1);
    o2e[j] = f32_bf16(v2);
  }
  if (isq) {
    short* q = Qb + ((long)(b * NH + hh) * SS + s) * HD;
    *(short4*)&q[t0] = o1;
    *(short4*)&q[t0 + 64] = o2;
  } else {
    short* k = Kb + ((long)(b * NKVH + (hh - 32)) * SS + s) * HD;
    *(short4*)&k[t0] = o1;
    *(short4*)&k[t0 + 64] = o2;
  }
}

// ---------------------------------------------------------------- V transpose scatter
// Round 16: reads vectorized (short4 = 4 d-values per load, 8 loads/thread vs 32
// scalar). Writes unchanged (lane l -> consecutive s: 128B coalesced per row).
__global__ __launch_bounds__(256) void v_scatter_kernel(const short* __restrict__ qkv,
                                                        short* __restrict__ Vtb) {
  int bid = blockIdx.x;                 // 512 = B * NKVH * (SS/64)
  int s0 = (bid & 31) << 6;
  int kvh = (bid >> 5) & 7;
  int b = bid >> 8;
  const short* src = qkv + (long)(b * SS + s0) * QKVN + 5120 + kvh * HD;
  short* dst = Vtb + ((long)(b * NKVH + kvh) * HD) * SS + s0;
  int w = threadIdx.x >> 6, l = threadIdx.x & 63;
#pragma unroll
  for (int it = 0; it < 8; ++it) {
    int d0 = (it << 4) + (w << 2);      // all multiples of 4 in [0,128)
    short4 v = *(const short4*)&src[(long)l * QKVN + d0];
    dst[(long)(d0 + 0) * SS + l] = v.x;
    dst[(long)(d0 + 1) * SS + l] = v.y;
    dst[(long)(d0 + 2) * SS + l] = v.z;
    dst[(long)(d0 + 3) * SS + l] = v.w;
  }
}

// ---------------------------------------------------------------- GEMM 256x256 BK=64, per-phase stage interleave
// Round-15 proven best (240us QKV): one half-tile staged per phase (m196 fine
// interleave), exact vmcnt(0) boundary (4 outstanding halves, all needed at
// t+1 phase 0), slot^=row&7 swizzle both-sides (0 conflicts), square per-XCD
// supertiles (FETCH 352->180MB). Plain __launch_bounds__(512) — NEVER pass
// min-waves (VGPR cap = 256/N; rounds 6/11 spilled). acc=128 AGPR -> 1 block/CU
// structurally; 8 configs all ~33-36% MfmaUtil = in-context plateau. FROZEN.
#define STAGEH_A(kt, bsel, h)                                                       \
  {                                                                                 \
    const long kb_ = (long)(kt) << 6;                                               \
    _Pragma("unroll") for (int j_ = 0; j_ < 2; j_++) {                              \
      const int idx_ = tid + j_ * 512;                                              \
      const int r_ = (idx_ >> 3) + (h) * 128;                                       \
      const int s_ = idx_ & 7;                                                      \
      const int ss_ = s_ ^ (r_ & 7);                                                \
      async16(Ag0 + (long)r_ * K + kb_ + ss_ * 8, &Abuf[bsel][r_ * 64 + s_ * 8]);   \
    }                                                                               \
  }

#define STAGEH_B(kt, bsel, h)                                                       \
  {                                                                                 \
    const long kb_ = (long)(kt) << 6;                                               \
    _Pragma("unroll") for (int j_ = 0; j_ < 2; j_++) {                              \
      const int idx_ = tid + j_ * 512;                                              \
      const int r_ = (idx_ >> 3) + (h) * 128;                                       \
      const int s_ = idx_ & 7;                                                      \
      const int ss_ = s_ ^ (r_ & 7);                                                \
      async16(Bg0 + (long)r_ * K + kb_ + ss_ * 8, &Bbuf[bsel][r_ * 64 + s_ * 8]);   \
    }                                                                               \
  }

// load A fragments for phase p into named frag pair
#define LDA(dst, p)                                                                 \
  {                                                                                 \
    _Pragma("unroll") for (int mi = 0; mi < 2; mi++)                                \
      _Pragma("unroll") for (int kk = 0; kk < 2; kk++)                              \
        dst[mi][kk] = *(const bf16x8*)&Ac[(((p) * 2 + mi) * 16 + l16) * 64 +        \
                                          ((((kk << 2) + quad) ^ xr) << 3)];        \
  }

// phase tail: barrier-aligned MFMA cluster (template-faithful)
#define PHTAIL(src, p)                                                              \
  {                                                                                 \
    __builtin_amdgcn_s_barrier();                                                   \
    asm volatile("s_waitcnt lgkmcnt(0)" ::: "memory");                              \
    __builtin_amdgcn_sched_barrier(0);                                              \
    __builtin_amdgcn_s_setprio(1);                                                  \
    _Pragma("unroll") for (int mi = 0; mi < 2; mi++)                                \
      _Pragma("unroll") for (int nr = 0; nr < 4; nr++)                              \
        _Pragma("unroll") for (int kk = 0; kk < 2; kk++)                            \
          acc[(p) * 2 + mi][nr] = __builtin_amdgcn_mfma_f32_16x16x32_bf16(          \
              src[mi][kk], bfr[nr][kk], acc[(p) * 2 + mi][nr], 0, 0, 0);            \
    __builtin_amdgcn_s_setprio(0);                                                  \
    __builtin_amdgcn_s_barrier();                                                   \
  }

template <int STORE_BF16>
__global__ __launch_bounds__(512) void gemm256_kernel(const short* __restrict__ A,
    const short* __restrict__ B, void* __restrict__ Cv, int M, int N, int K, int gx) {
  __shared__ __align__(16) short Abuf[2][256 * 64];   // 64KB
  __shared__ __align__(16) short Bbuf[2][256 * 64];   // 64KB
  const int tid = threadIdx.x;
  const int lane = tid & 63, wave = tid >> 6;
  const int quad = lane >> 4, l16 = lane & 15;
  const int wm = wave >> 2;          // 0..1: M-half
  const int wn = wave & 3;           // 0..3: N-quarter
  const int xr = l16 & 7;            // read-side XOR key

  // Square per-XCD supertile decode (gy = 16 both call sites):
  const int bid = (int)blockIdx.x;
  const int xcd = bid & 7;
  const int i = bid >> 3;            // 0 .. nwg/8-1
  const int cpb = gx >> 2;           // patch cols (6 QKV, 4 O-proj)
  const int prow = i & 7;            // patch rows = 8 (gy/2)
  const int pcol = i >> 3;
  const int m0 = (((xcd >> 2) << 3) + prow) << 8;
  const int n0 = ((xcd & 3) * cpb + pcol) << 8;

  const short* Ag0 = A + (long)m0 * K;
  const short* Bg0 = B + (long)n0 * K;

  f32x4 acc[8][4];
#pragma unroll
  for (int mr = 0; mr < 8; mr++)
#pragma unroll
    for (int nr = 0; nr < 4; nr++) acc[mr][nr] = (f32x4){0.f, 0.f, 0.f, 0.f};

  const int nk = K >> 6;

  // prologue: stage all 4 halves of tile 0 into buf0, exact drain, align
  STAGEH_A(0, 0, 0)
  STAGEH_A(0, 0, 1)
  STAGEH_B(0, 0, 0)
  STAGEH_B(0, 0, 1)
  asm volatile("s_waitcnt vmcnt(0)" ::: "memory");
  __builtin_amdgcn_sched_barrier(0);
  __builtin_amdgcn_s_barrier();

  int cur = 0;
#pragma unroll 1
  for (int kt = 0; kt < nk; ++kt) {
    const short* Ac = &Abuf[cur][wm * 128 * 64];
    const short* Bc = &Bbuf[cur][wn * 64 * 64];
    const int nb = cur ^ 1;
    const bool pf = (kt + 1 < nk);

    bf16x8 afr[2][2];
    bf16x8 bfr[4][2];

    // ---- phase 0: B-frags(8) + A-quad0(4); stage Ah0(t+1)
#pragma unroll
    for (int nr = 0; nr < 4; nr++)
#pragma unroll
      for (int kk = 0; kk < 2; kk++)
        bfr[nr][kk] = *(const bf16x8*)&Bc[(nr * 16 + l16) * 64 +
                                          ((((kk << 2) + quad) ^ xr) << 3)];
    LDA(afr, 0)
    if (pf) { STAGEH_A(kt + 1, nb, 0) }
    PHTAIL(afr, 0)

    // ---- phase 1: A-quad1; stage Ah1(t+1)
    LDA(afr, 1)
    if (pf) { STAGEH_A(kt + 1, nb, 1) }
    PHTAIL(afr, 1)

    // ---- phase 2: A-quad2; stage Bh0(t+1)
    LDA(afr, 2)
    if (pf) { STAGEH_B(kt + 1, nb, 0) }
    PHTAIL(afr, 2)

    // ---- phase 3: A-quad3; stage Bh1(t+1)
    LDA(afr, 3)
    if (pf) { STAGEH_B(kt + 1, nb, 1) }
    PHTAIL(afr, 3)

    // tile boundary: exact counted drain (only t+1's 4 stages outstanding),
    // then WAR/RAW barrier; flip buffers.
    asm volatile("s_waitcnt vmcnt(0)" ::: "memory");
    __builtin_amdgcn_sched_barrier(0);
    __builtin_amdgcn_s_barrier();
    cur ^= 1;
  }

  // epilogue
#pragma unroll
  for (int mr = 0; mr < 8; mr++)
#pragma unroll
    for (int nr = 0; nr < 4; nr++)
#pragma unroll
      for (int r = 0; r < 4; r++) {
        long row = m0 + wm * 128 + mr * 16 + quad * 4 + r;
        long col = n0 + wn * 64 + nr * 16 + l16;
        if (STORE_BF16)
          ((short*)Cv)[row * N + col] = f32_bf16(acc[mr][nr][r]);
        else
          ((float*)Cv)[row * N + col] = acc[mr][nr][r];
      }
}

// ---------------------------------------------------------------- flash attention v9 (proven round 9)
// Block-cooperative K+V LDS staging (4x traffic cut), uniform 34-step causal
// pairing, counted-vmcnt pipeline, XOR-swizzled tiles. Frozen.
#define PSS 72   // P LDS row stride (elements): 144B, 16B-multiple

#define STAGEK(j0_)                                                                 \
  {                                                                                 \
    _Pragma("unroll") for (int i_ = 0; i_ < 4; i_++) {                              \
      const int idx_ = tid + i_ * 256;                                              \
      const int r_ = idx_ >> 4, s_ = idx_ & 15;                                     \
      async16(Kb + (long)((j0_) + r_) * HD + ((s_ ^ (r_ & 7)) << 3),                \
              &Ks[r_ * 128 + (s_ << 3)]);                                           \
    }                                                                               \
  }

#define STAGEV(j0_)                                                                 \
  {                                                                                 \
    _Pragma("unroll") for (int i_ = 0; i_ < 4; i_++) {                              \
      const int idx_ = tid + i_ * 256;                                              \
      const int r_ = idx_ >> 3, s_ = idx_ & 7;                                      \
      async16(Vb + (long)r_ * SS + (j0_) + ((s_ ^ (r_ & 7)) << 3),                  \
              &Vs[r_ * 64 + (s_ << 3)]);                                            \
    }                                                                               \
  }

__global__ __launch_bounds__(256, 2) void flash_attn_kernel(const short* __restrict__ Q,
    const short* __restrict__ Kt, const short* __restrict__ Vt, short* __restrict__ O) {
  __shared__ __align__(16) short Ks[64 * 128];   // 16KB K tile (swizzled)
  __shared__ __align__(16) short Vs[128 * 64];   // 16KB V tile (swizzled, [d][key])
  __shared__ __align__(16) short Ps[4][32 * PSS];
  const int tid = threadIdx.x;
  const int wave = tid >> 6, lane = tid & 63;
  const int quad = lane >> 4, l16 = lane & 15;
  const int k7 = l16 & 7;                        // read-side XOR key

  // XCD co-location decode: 512 blocks; blocks sharing (b,kvh) share bid%8.
  const int flat = blockIdx.x;
  const int xcd = flat & 7;
  const int kk_ = flat >> 3;          // 0..63
  const int gsel = kk_ >> 5;          // 0..1
  const int jj = kk_ & 31;            // 0..31
  const int g = xcd * 2 + gsel;       // 0..15 = (b,kvh) group
  const int b = g >> 3, kvh = g & 7;
  const int h = (kvh << 2) + (jj >> 3);
  const int qb0 = jj & 7;

  const short* Kb = Kt + (long)(b * NKVH + kvh) * SS * HD;
  const short* Vb = Vt + (long)(b * NKVH + kvh) * HD * SS;
  short* Pw = &Ps[wave][0];

  // Two causal-complementary 128-row block-tiles: steps = (2qb+2)+(32-2qb) = 34.
#pragma unroll 1
  for (int half = 0; half < 2; half++) {
    const int qb = half ? (15 - qb0) : qb0;
    const int q0b = qb << 7;
    const int q0w = q0b + (wave << 5);
    const int nfull = q0w >> 6;            // this wave's last (masked) tile
    const int tsteps = (q0b >> 6) + 2;     // block-uniform step count

    const short* Qw = Q + ((long)(b * NH + h) * SS + q0w) * HD;
    bf16x8 qf[2][4];
#pragma unroll
    for (int i = 0; i < 2; i++)
#pragma unroll
      for (int kk = 0; kk < 4; kk++)
        qf[i][kk] = *(const bf16x8*)&Qw[(i * 16 + l16) * HD + kk * 32 + quad * 8];
    // drain Q loads so staging vmcnt counts stay exact
    asm volatile("s_waitcnt vmcnt(0)" ::: "memory");
    __builtin_amdgcn_sched_barrier(0);

    f32x4 oacc[2][8];
#pragma unroll
    for (int i = 0; i < 2; i++)
#pragma unroll
      for (int jo = 0; jo < 8; jo++) oacc[i][jo] = (f32x4){0.f, 0.f, 0.f, 0.f};
    float l_i[2][4];
#pragma unroll
    for (int i = 0; i < 2; i++)
#pragma unroll
      for (int r = 0; r < 4; r++) l_i[i][r] = 0.f;

    // prologue: stage K[0] then V[0]  (outstanding: K 4 oldest, V 4 newest)
    STAGEK(0)
    STAGEV(0)

#pragma unroll 1
    for (int t = 0; t < tsteps; t++) {
      const int j0 = t << 6;
      const bool active = (t <= nfull);
      const bool havenext = (t + 1 < tsteps);

      // top: retire K[t] (V[t] may still fly), align block
      asm volatile("s_waitcnt vmcnt(4)" ::: "memory");
      __builtin_amdgcn_sched_barrier(0);
      __builtin_amdgcn_s_barrier();
      __builtin_amdgcn_sched_barrier(0);

      f32x4 sc[2][4];
      if (active) {
        // QK from LDS K tile
        bf16x8 kf[16];
#pragma unroll
        for (int kk = 0; kk < 4; kk++)
#pragma unroll
          for (int j = 0; j < 4; j++)
            kf[kk * 4 + j] = *(const bf16x8*)&Ks[(j * 16 + l16) * 128 +
                                                 ((((kk << 2) + quad) ^ k7) << 3)];
#pragma unroll
        for (int i = 0; i < 2; i++)
#pragma unroll
          for (int j = 0; j < 4; j++) sc[i][j] = (f32x4){0.f, 0.f, 0.f, 0.f};
        __builtin_amdgcn_s_setprio(1);
#pragma unroll
        for (int kk = 0; kk < 4; kk++)
#pragma unroll
          for (int i = 0; i < 2; i++)
#pragma unroll
            for (int j = 0; j < 4; j++)
              sc[i][j] = __builtin_amdgcn_mfma_f32_16x16x32_bf16(
                  qf[i][kk], kf[kk * 4 + j], sc[i][j], 0, 0, 0);
        __builtin_amdgcn_s_setprio(0);
      }

      // all waves done reading Ks[t]
      __builtin_amdgcn_s_barrier();
      __builtin_amdgcn_sched_barrier(0);
      if (havenext) STAGEK(j0 + 64)   // hides under exp/P/PV

      if (active) {
        if (t == nfull) {
#pragma unroll
          for (int i = 0; i < 2; i++)
#pragma unroll
            for (int r = 0; r < 4; r++) {
              int row = q0w + i * 16 + quad * 4 + r;
#pragma unroll
              for (int j = 0; j < 4; j++) {
                int col = j0 + j * 16 + l16;
                if (col > row) sc[i][j][r] = -3.0e38f;
              }
            }
        }
        // p = exp(s); per-lane row-sum partials (max-free)
#pragma unroll
        for (int i = 0; i < 2; i++)
#pragma unroll
          for (int r = 0; r < 4; r++) {
            float ps = 0.f;
#pragma unroll
            for (int j = 0; j < 4; j++) {
              float p = __builtin_amdgcn_exp2f(sc[i][j][r] * LOG2E);
              sc[i][j][r] = p;
              ps += p;
            }
            l_i[i][r] += ps;
          }
        // P: C-layout -> per-wave LDS -> A-layout
#pragma unroll
        for (int i = 0; i < 2; i++)
#pragma unroll
          for (int j = 0; j < 4; j++)
#pragma unroll
            for (int r = 0; r < 4; r++)
              Pw[(i * 16 + quad * 4 + r) * PSS + j * 16 + l16] = f32_bf16(sc[i][j][r]);
      }

      // retire V[t] (K[t+1] may still fly), align block
      if (havenext) {
        asm volatile("s_waitcnt vmcnt(4)" ::: "memory");
      } else {
        asm volatile("s_waitcnt vmcnt(0)" ::: "memory");
      }
      __builtin_amdgcn_sched_barrier(0);
      __builtin_amdgcn_s_barrier();
      __builtin_amdgcn_sched_barrier(0);

      if (active) {
        asm volatile("s_waitcnt lgkmcnt(0)" ::: "memory");   // P writes landed
        bf16x8 ap[2][2];
#pragma unroll
        for (int kv = 0; kv < 2; kv++) {
          ap[kv][0] = *(const bf16x8*)&Pw[l16 * PSS + kv * 32 + quad * 8];
          ap[kv][1] = *(const bf16x8*)&Pw[(16 + l16) * PSS + kv * 32 + quad * 8];
        }
        // PV from LDS V tile
        __builtin_amdgcn_s_setprio(1);
#pragma unroll
        for (int jo = 0; jo < 8; jo++) {
          bf16x8 v0 = *(const bf16x8*)&Vs[(jo * 16 + l16) * 64 + ((quad ^ k7) << 3)];
          oacc[0][jo] = __builtin_amdgcn_mfma_f32_16x16x32_bf16(ap[0][0], v0,
                                                                oacc[0][jo], 0, 0, 0);
          oacc[1][jo] = __builtin_amdgcn_mfma_f32_16x16x32_bf16(ap[0][1], v0,
                                                                oacc[1][jo], 0, 0, 0);
        }
#pragma unroll
        for (int jo = 0; jo < 8; jo++) {
          bf16x8 v1 = *(const bf16x8*)&Vs[(jo * 16 + l16) * 64 +
                                          (((4 + quad) ^ k7) << 3)];
          oacc[0][jo] = __builtin_amdgcn_mfma_f32_16x16x32_bf16(ap[1][0], v1,
                                                                oacc[0][jo], 0, 0, 0);
          oacc[1][jo] = __builtin_amdgcn_mfma_f32_16x16x32_bf16(ap[1][1], v1,
                                                                oacc[1][jo], 0, 0, 0);
        }
        __builtin_amdgcn_s_setprio(0);
      }

      // all waves done reading Vs[t]
      __builtin_amdgcn_s_barrier();
      __builtin_amdgcn_sched_barrier(0);
      if (havenext) STAGEV(j0 + 64)   // hides under next QK
    }

    // epilogue: reduce l across the 16 lanes of each quad (once), store
    short* Ob = O + (long)(b * SS + q0w) * DD + h * HD;
#pragma unroll
    for (int i = 0; i < 2; i++)
#pragma unroll
      for (int r = 0; r < 4; r++) {
        float s = l_i[i][r];
        s += __shfl_xor(s, 1, 64);
        s += __shfl_xor(s, 2, 64);
        s += __shfl_xor(s, 4, 64);
        s += __shfl_xor(s, 8, 64);
        float inv = 1.0f / s;
        int row = i * 16 + quad * 4 + r;
#pragma unroll
        for (int jo = 0; jo < 8; jo++)
          Ob[(long)row * DD + jo * 16 + l16] = f32_bf16(oacc[i][jo][r] * inv);
      }
  }
}

// ---------------------------------------------------------------- launch
extern "C" void kernel_launch(void* const* d_in, const int* in_sizes, int n_in,
                              void* d_out, int out_size, void* d_ws, size_t ws_size,
                              hipStream_t stream) {
  (void)in_sizes; (void)n_in; (void)out_size; (void)ws_size;
  const float* x    = (const float*)d_in[0];
  const float* Wqkv = (const float*)d_in[1];
  const float* Wo   = (const float*)d_in[2];
  char* ws = (char*)d_ws;
  short* xb    = (short*)(ws + 0);            // x bf16 (33.5MB); reused as attn out
  short* wqkvb = (short*)(ws + 33554432);     // Wqkv bf16 (50.3MB)
  short* qkvb  = (short*)(ws + 83886080);     // qkv (50.3MB); reused as Wo bf16
  short* Qb    = (short*)(ws + 134217728);    // 33.5MB
  short* Kb    = (short*)(ws + 167772160);    // 8.4MB
  short* Vtb   = (short*)(ws + 176160768);    // 8.4MB
  float* cosT  = (float*)(ws + 184549376);    // 0.5MB
  float* sinT  = (float*)(ws + 185073664);    // 0.5MB
  short* wob   = qkvb;
  short* attnb = xb;

  cast_bf16_kernel<<<16384, 256, 0, stream>>>(x, xb, 4194304);
  cast_bf16_kernel<<<24576, 256, 0, stream>>>(Wqkv, wqkvb, 6291456);
  gemm256_kernel<1><<<dim3((QKVN / 256) * (MROWS / 256)), 512, 0, stream>>>(
      xb, wqkvb, (void*)qkvb, MROWS, QKVN, DD, QKVN / 256);
  rope_tables_kernel<<<512, 256, 0, stream>>>(cosT, sinT);
  rope_scatter_kernel<<<10240, 256, 0, stream>>>(qkvb, cosT, sinT, Qb, Kb);
  v_scatter_kernel<<<512, 256, 0, stream>>>(qkvb, Vtb);
  cast_bf16_kernel<<<16384, 256, 0, stream>>>(Wo, wob, 4194304);   // overwrites qkvb (dead)
  flash_attn_kernel<<<512, 256, 0, stream>>>(Qb, Kb, Vtb, attnb);
  gemm256_kernel<0><<<dim3((DD / 256) * (MROWS / 256)), 512, 0, stream>>>(
      attnb, wob, d_out, MROWS, DD, DD, DD / 256);
}